// Round 4
// baseline (984.256 us; speedup 1.0000x reference)
//
#include <hip/hip_runtime.h>
#include <cstdint>

#define N_NODES 100000
#define N_EDGES 1600000
#define F_IN 128
#define HID 128
#define N_CLS 40
#define NB_SCAN ((N_NODES + 255) / 256)

typedef __attribute__((ext_vector_type(8))) short bf16x8;
typedef __attribute__((ext_vector_type(4))) float f32x4;

__device__ __forceinline__ unsigned short f2b(float f) {  // RNE f32->bf16
    unsigned u = __float_as_uint(f);
    return (unsigned short)((u + 0x7fffu + ((u >> 16) & 1u)) >> 16);
}
__device__ __forceinline__ float b2f(unsigned us) {
    return __uint_as_float(us << 16);
}

// Tiled activation layout: Hc[tile j][node][16 cols], j = col/16.
// Element (node, col) lives at ((size_t)(col>>4) * N + node) * 16 + (col & 15).

// ---------------------------------------------------------------------------
// Edge dtype detection (int64 vs int32 edge_index). Deterministic.
// ---------------------------------------------------------------------------
__global__ __launch_bounds__(256) void k_detect(const int* __restrict__ e, int* __restrict__ flag) {
    __shared__ int sor;
    if (threadIdx.x == 0) sor = 0;
    __syncthreads();
    atomicOr(&sor, e[threadIdx.x * 2 + 1]);
    __syncthreads();
    if (threadIdx.x == 0) flag[0] = (sor == 0) ? 1 : 0;  // 1 = int64 layout
}

__device__ __forceinline__ int edge_at(const int* e, const int* flag, int which, int i) {
    return flag[0] ? e[2 * ((size_t)which * N_EDGES + i)] : e[(size_t)which * N_EDGES + i];
}

__global__ __launch_bounds__(256) void k_count(const int* __restrict__ e, const int* __restrict__ flag,
                                               int* __restrict__ cnt, int E) {
    int i = blockIdx.x * 256 + threadIdx.x;
    if (i < E) atomicAdd(&cnt[edge_at(e, flag, 1, i)], 1);
}

__global__ __launch_bounds__(256) void k_dis(const int* __restrict__ cnt, float* __restrict__ dis, int N) {
    int i = blockIdx.x * 256 + threadIdx.x;
    if (i < N) dis[i] = rsqrtf((float)(cnt[i] + 1));
}

// ---------------- exclusive scan of cnt -> rowptr --------------------------
__global__ __launch_bounds__(256) void k_scan1(const int* __restrict__ cnt, int* __restrict__ part, int N) {
    __shared__ int s[256];
    int i = blockIdx.x * 256 + threadIdx.x;
    s[threadIdx.x] = (i < N) ? cnt[i] : 0;
    __syncthreads();
    for (int off = 128; off; off >>= 1) {
        if (threadIdx.x < off) s[threadIdx.x] += s[threadIdx.x + off];
        __syncthreads();
    }
    if (threadIdx.x == 0) part[blockIdx.x] = s[0];
}

__global__ __launch_bounds__(512) void k_scan2(const int* __restrict__ part, int* __restrict__ part_ex, int nb) {
    __shared__ int s[512];
    int t = threadIdx.x;
    s[t] = (t < nb) ? part[t] : 0;
    __syncthreads();
    for (int off = 1; off < 512; off <<= 1) {
        int v = (t >= off) ? s[t - off] : 0;
        __syncthreads();
        s[t] += v;
        __syncthreads();
    }
    if (t < nb) part_ex[t] = (t == 0) ? 0 : s[t - 1];
}

__global__ __launch_bounds__(256) void k_scan3(const int* __restrict__ cnt, const int* __restrict__ part_ex,
                                               int* __restrict__ rowptr, int N, int E) {
    __shared__ int s[256];
    int i = blockIdx.x * 256 + threadIdx.x;
    int c = (i < N) ? cnt[i] : 0;
    s[threadIdx.x] = c;
    __syncthreads();
    for (int off = 1; off < 256; off <<= 1) {
        int v = (threadIdx.x >= off) ? s[threadIdx.x - off] : 0;
        __syncthreads();
        s[threadIdx.x] += v;
        __syncthreads();
    }
    if (i < N) rowptr[i] = part_ex[blockIdx.x] + s[threadIdx.x] - c;
    if (i == 0) rowptr[N] = E;
}

__global__ __launch_bounds__(256) void k_fill(const int* __restrict__ e, const int* __restrict__ flag,
                                              const int* __restrict__ rowptr, int* __restrict__ fill,
                                              int* __restrict__ es, int E) {
    int i = blockIdx.x * 256 + threadIdx.x;
    if (i >= E) return;
    int s = edge_at(e, flag, 0, i);
    int d = edge_at(e, flag, 1, i);
    int pos = rowptr[d] + atomicAdd(&fill[d], 1);
    es[pos] = s;
}

// Wt[col][k] = bf16(W[k][col]), zero-padded to outp cols
__global__ __launch_bounds__(256) void k_wt(const float* __restrict__ W, unsigned short* __restrict__ Wt,
                                            int outc, int outp) {
    int idx = blockIdx.x * 256 + threadIdx.x;
    if (idx >= outp * 128) return;
    int col = idx >> 7, k = idx & 127;
    Wt[idx] = (col < outc) ? f2b(W[(size_t)k * outc + col]) : (unsigned short)0;
}

// ---------------------------------------------------------------------------
// MFMA bf16 GEMM. INMODE: 0 = fp32 row-major input, 1 = bf16 tiled input.
// OUTMODE: 0 = bf16 tiled output, 1 = fp32 row-major [N,outc] + bias.
// Block = 64 rows, 4 waves x 16 rows.
// ---------------------------------------------------------------------------
template <int NT, int INMODE, int OUTMODE>
__global__ __launch_bounds__(256) void k_gemm_mfma(const void* __restrict__ Xv,
                                                   const unsigned short* __restrict__ Wt,
                                                   void* __restrict__ HoutV,
                                                   const float* __restrict__ bias, int N, int outc) {
    constexpr int OUTP = NT * 16;
    __shared__ __align__(16) unsigned short sX[64 * 136];
    __shared__ __align__(16) unsigned short sW[OUTP * 136];
    const int tid  = threadIdx.x;
    const int row0 = blockIdx.x * 64;

    if (INMODE == 0) {
        const float* X = (const float*)Xv;
        for (int c = tid; c < 64 * 16; c += 256) {
            int r = c >> 4, off = c & 15, row = row0 + r;
            unsigned short tmp[8];
            if (row < N) {
                const float* p = X + (size_t)row * 128 + off * 8;
#pragma unroll
                for (int j = 0; j < 8; ++j) tmp[j] = f2b(p[j]);
            } else {
#pragma unroll
                for (int j = 0; j < 8; ++j) tmp[j] = 0;
            }
            *(uint4*)(&sX[r * 136 + off * 8]) = *(uint4*)tmp;
        }
    } else {
        const unsigned short* X = (const unsigned short*)Xv;
        for (int c = tid; c < 64 * 16; c += 256) {
            int r = c >> 4, q = c & 15;      // q: tile-half units of 16B
            int j = q >> 1, h = q & 1;
            int row = row0 + r;
            uint4 v = make_uint4(0, 0, 0, 0);
            if (row < N) v = *(const uint4*)(X + ((size_t)j * N + row) * 16 + h * 8);
            *(uint4*)(&sX[r * 136 + j * 16 + h * 8]) = v;
        }
    }
    for (int c = tid; c < OUTP * 16; c += 256) {
        int r = c >> 4, off = c & 15;
        *(uint4*)(&sW[r * 136 + off * 8]) = *(const uint4*)(Wt + (size_t)r * 128 + off * 8);
    }
    __syncthreads();

    const int wave = tid >> 6, lane = tid & 63;
    const int l15 = lane & 15, g = lane >> 4;
    const int arow = (wave << 4) + l15;

    f32x4 acc[NT];
#pragma unroll
    for (int n = 0; n < NT; ++n) acc[n] = (f32x4){0.f, 0.f, 0.f, 0.f};

#pragma unroll
    for (int kk = 0; kk < 4; ++kk) {
        bf16x8 a = *(const bf16x8*)(&sX[arow * 136 + kk * 32 + g * 8]);
#pragma unroll
        for (int n = 0; n < NT; ++n) {
            bf16x8 b = *(const bf16x8*)(&sW[(n * 16 + l15) * 136 + kk * 32 + g * 8]);
            acc[n] = __builtin_amdgcn_mfma_f32_16x16x32_bf16(a, b, acc[n], 0, 0, 0);
        }
    }

    if (OUTMODE == 0) {
        unsigned short* O = (unsigned short*)HoutV;
#pragma unroll
        for (int n = 0; n < NT; ++n) {
#pragma unroll
            for (int r = 0; r < 4; ++r) {
                int row = row0 + (wave << 4) + g * 4 + r;
                if (row < N) O[((size_t)n * N + row) * 16 + l15] = f2b(acc[n][r]);
            }
        }
    } else {
        float* O = (float*)HoutV;
#pragma unroll
        for (int n = 0; n < NT; ++n) {
            int col = n * 16 + l15;
            if (col < outc) {
                float bb = bias[col];
#pragma unroll
                for (int r = 0; r < 4; ++r) {
                    int row = row0 + (wave << 4) + g * 4 + r;
                    if (row < N) O[(size_t)row * outc + col] = acc[n][r] + bb;
                }
            }
        }
    }
}

// ---------------------------------------------------------------------------
// Feature-tiled CSR pull. grid = 8 * ceil(N/4); pass = blockIdx & 7 so that
// (round-robin XCD dispatch) XCD j works only on tile j -> 3.2MB tile stays
// resident in that XCD's 4MB L2 with ~16x reuse. Wave per node: 8 edge-groups
// x 8 col-pairs; shuffle-xor reduce over groups; self-loop (+bias+relu) fused.
// ---------------------------------------------------------------------------
template <bool RELU_BIAS>
__global__ __launch_bounds__(256) void k_pull_tiled(const int* __restrict__ rowptr, const int* __restrict__ es,
                                                    const float* __restrict__ dis,
                                                    const unsigned short* __restrict__ Hin,
                                                    const float* __restrict__ bias,
                                                    unsigned short* __restrict__ Hout, int N) {
    const int pass = blockIdx.x & 7;
    const int node = (blockIdx.x >> 3) * 4 + (threadIdx.x >> 6);
    if (node >= N) return;
    const int lane = threadIdx.x & 63;
    const int eg = lane >> 3, cp = lane & 7;

    const unsigned short* Ht = Hin + (size_t)pass * N * 16;
    const int  beg = rowptr[node], end = rowptr[node + 1];
    const float dd = dis[node];

    float ax = 0.f, ay = 0.f;
    for (int p = beg + eg; p < end; p += 8) {
        int      s = es[p];
        float    n = dis[s] * dd;
        unsigned u = *(const unsigned*)(Ht + (size_t)s * 16 + cp * 2);
        ax = fmaf(b2f(u & 0xffffu), n, ax);
        ay = fmaf(b2f(u >> 16), n, ay);
    }
    ax += __shfl_xor(ax, 8);  ay += __shfl_xor(ay, 8);
    ax += __shfl_xor(ax, 16); ay += __shfl_xor(ay, 16);
    ax += __shfl_xor(ax, 32); ay += __shfl_xor(ay, 32);

    if (eg == 0) {
        unsigned u  = *(const unsigned*)(Ht + (size_t)node * 16 + cp * 2);
        float    d2 = dd * dd;
        ax = fmaf(b2f(u & 0xffffu), d2, ax);
        ay = fmaf(b2f(u >> 16), d2, ay);
        if (RELU_BIAS) {
            ax = fmaxf(ax + bias[pass * 16 + cp * 2], 0.f);
            ay = fmaxf(ay + bias[pass * 16 + cp * 2 + 1], 0.f);
        }
        unsigned o = (unsigned)f2b(ax) | ((unsigned)f2b(ay) << 16);
        *(unsigned*)(Hout + ((size_t)pass * N + node) * 16 + cp * 2) = o;
    }
}

// log_softmax over rows of [N,40] fp32 (bias already added by GEMM epilogue)
__global__ __launch_bounds__(256) void k_lsm40(const float* __restrict__ H3, float* __restrict__ out, int N) {
    int node = blockIdx.x * 4 + (threadIdx.x >> 6);
    if (node >= N) return;
    int   lane = threadIdx.x & 63;
    float x = 0.f, m = -3.0e38f;
    if (lane < 40) { x = H3[(size_t)node * 40 + lane]; m = x; }
    for (int off = 32; off; off >>= 1) m = fmaxf(m, __shfl_xor(m, off));
    float sum = (lane < 40) ? __expf(x - m) : 0.f;
    for (int off = 32; off; off >>= 1) sum += __shfl_xor(sum, off);
    float ls = __logf(sum);
    if (lane < 40) out[(size_t)node * 40 + lane] = x - m - ls;
}

extern "C" void kernel_launch(void* const* d_in, const int* in_sizes, int n_in,
                              void* d_out, int out_size, void* d_ws, size_t ws_size,
                              hipStream_t stream) {
    const float* x   = (const float*)d_in[0];
    const int*   ei  = (const int*)d_in[1];
    const float* W1  = (const float*)d_in[2];
    const float* b1  = (const float*)d_in[3];
    const float* W2  = (const float*)d_in[4];
    const float* b2  = (const float*)d_in[5];
    const float* W3  = (const float*)d_in[6];
    const float* b3  = (const float*)d_in[7];
    float*       out = (float*)d_out;
    const int    N = N_NODES, E = N_EDGES;

    // workspace layout (bytes) — ~83 MB total
    char*           ws      = (char*)d_ws;
    int*            flag    = (int*)ws;
    int*            cnt     = (int*)(ws + 1 * (1u << 20));
    int*            fillarr = (int*)(ws + 2 * (1u << 20));
    float*          dis     = (float*)(ws + 3 * (1u << 20));
    int*            rowptr  = (int*)(ws + 4 * (1u << 20));
    int*            part    = (int*)(ws + 5 * (1u << 20));
    int*            part_ex = (int*)(ws + 5 * (1u << 20) + 65536);
    unsigned short* Wt1     = (unsigned short*)(ws + 5 * (1u << 20) + 131072);  // 32 KB
    unsigned short* Wt2     = Wt1 + 128 * 128;                                   // 32 KB
    unsigned short* Wt3     = Wt2 + 128 * 128;                                   // 12 KB
    int*            es      = (int*)(ws + 6 * (size_t)(1u << 20));               // 6.4 MB
    unsigned short* T1      = (unsigned short*)(ws + 13 * (size_t)(1u << 20));   // 25.6 MB (tiled)
    unsigned short* T2      = (unsigned short*)(ws + 40 * (size_t)(1u << 20));   // 25.6 MB (tiled)
    float*          H3      = (float*)(ws + 67 * (size_t)(1u << 20));            // 16 MB

    // ---- CSR build + weight prep ----
    k_detect<<<1, 256, 0, stream>>>(ei, flag);
    hipMemsetAsync(cnt, 0, N * sizeof(int), stream);
    hipMemsetAsync(fillarr, 0, N * sizeof(int), stream);
    k_count<<<(E + 255) / 256, 256, 0, stream>>>(ei, flag, cnt, E);
    k_dis<<<(N + 255) / 256, 256, 0, stream>>>(cnt, dis, N);
    k_scan1<<<NB_SCAN, 256, 0, stream>>>(cnt, part, N);
    k_scan2<<<1, 512, 0, stream>>>(part, part_ex, NB_SCAN);
    k_scan3<<<NB_SCAN, 256, 0, stream>>>(cnt, part_ex, rowptr, N, E);
    k_fill<<<(E + 255) / 256, 256, 0, stream>>>(ei, flag, rowptr, fillarr, es, E);
    k_wt<<<(128 * 128 + 255) / 256, 256, 0, stream>>>(W1, Wt1, 128, 128);
    k_wt<<<(128 * 128 + 255) / 256, 256, 0, stream>>>(W2, Wt2, 128, 128);
    k_wt<<<(48 * 128 + 255) / 256, 256, 0, stream>>>(W3, Wt3, 40, 48);

    const int gb = (N + 63) / 64;         // GEMM blocks
    const int pg = 8 * ((N + 3) / 4);     // pull grid (8 passes)

    // ---- layer 1 ----
    k_gemm_mfma<8, 0, 0><<<gb, 256, 0, stream>>>(x, Wt1, T1, nullptr, N, 128);
    k_pull_tiled<true><<<pg, 256, 0, stream>>>(rowptr, es, dis, T1, b1, T2, N);

    // ---- layer 2 ----
    k_gemm_mfma<8, 1, 0><<<gb, 256, 0, stream>>>(T2, Wt2, T1, nullptr, N, 128);
    k_pull_tiled<true><<<pg, 256, 0, stream>>>(rowptr, es, dis, T1, b2, T2, N);

    // ---- layer 3: aggregate first (A and W3 commute), then GEMM + lsm ----
    k_pull_tiled<false><<<pg, 256, 0, stream>>>(rowptr, es, dis, T2, nullptr, T1, N);
    k_gemm_mfma<3, 1, 1><<<gb, 256, 0, stream>>>(T1, Wt3, H3, b3, N, 40);
    k_lsm40<<<(N + 3) / 4, 256, 0, stream>>>(H3, out, N);
}

// Round 5
// 471.741 us; speedup vs baseline: 2.0864x; 2.0864x over previous
//
#include <hip/hip_runtime.h>
#include <cstdint>

#define N_NODES 100000
#define N_EDGES 1600000
#define F_IN 128
#define HID 128
#define N_CLS 40
#define NB_SCAN ((N_NODES + 255) / 256)

typedef __attribute__((ext_vector_type(8))) short bf16x8;
typedef __attribute__((ext_vector_type(4))) float f32x4;

__device__ __forceinline__ unsigned short f2b(float f) {  // RNE f32->bf16
    unsigned u = __float_as_uint(f);
    return (unsigned short)((u + 0x7fffu + ((u >> 16) & 1u)) >> 16);
}
__device__ __forceinline__ float b2f(unsigned us) {
    return __uint_as_float(us << 16);
}

// ---------------------------------------------------------------------------
// Edge dtype detection (int64 vs int32 edge_index). Deterministic.
// ---------------------------------------------------------------------------
__global__ __launch_bounds__(256) void k_detect(const int* __restrict__ e, int* __restrict__ flag) {
    __shared__ int sor;
    if (threadIdx.x == 0) sor = 0;
    __syncthreads();
    atomicOr(&sor, e[threadIdx.x * 2 + 1]);
    __syncthreads();
    if (threadIdx.x == 0) flag[0] = (sor == 0) ? 1 : 0;  // 1 = int64 layout
}

__device__ __forceinline__ int edge_at(const int* e, const int* flag, int which, int i) {
    return flag[0] ? e[2 * ((size_t)which * N_EDGES + i)] : e[(size_t)which * N_EDGES + i];
}

__global__ __launch_bounds__(256) void k_count(const int* __restrict__ e, const int* __restrict__ flag,
                                               int* __restrict__ cnt, int E) {
    int i = blockIdx.x * 256 + threadIdx.x;
    if (i < E) atomicAdd(&cnt[edge_at(e, flag, 1, i)], 1);
}

__global__ __launch_bounds__(256) void k_dis(const int* __restrict__ cnt, float* __restrict__ dis, int N) {
    int i = blockIdx.x * 256 + threadIdx.x;
    if (i < N) dis[i] = rsqrtf((float)(cnt[i] + 1));
}

// ---------------- exclusive scan of cnt -> rowptr --------------------------
__global__ __launch_bounds__(256) void k_scan1(const int* __restrict__ cnt, int* __restrict__ part, int N) {
    __shared__ int s[256];
    int i = blockIdx.x * 256 + threadIdx.x;
    s[threadIdx.x] = (i < N) ? cnt[i] : 0;
    __syncthreads();
    for (int off = 128; off; off >>= 1) {
        if (threadIdx.x < off) s[threadIdx.x] += s[threadIdx.x + off];
        __syncthreads();
    }
    if (threadIdx.x == 0) part[blockIdx.x] = s[0];
}

__global__ __launch_bounds__(512) void k_scan2(const int* __restrict__ part, int* __restrict__ part_ex, int nb) {
    __shared__ int s[512];
    int t = threadIdx.x;
    s[t] = (t < nb) ? part[t] : 0;
    __syncthreads();
    for (int off = 1; off < 512; off <<= 1) {
        int v = (t >= off) ? s[t - off] : 0;
        __syncthreads();
        s[t] += v;
        __syncthreads();
    }
    if (t < nb) part_ex[t] = (t == 0) ? 0 : s[t - 1];
}

__global__ __launch_bounds__(256) void k_scan3(const int* __restrict__ cnt, const int* __restrict__ part_ex,
                                               int* __restrict__ rowptr, int N, int E) {
    __shared__ int s[256];
    int i = blockIdx.x * 256 + threadIdx.x;
    int c = (i < N) ? cnt[i] : 0;
    s[threadIdx.x] = c;
    __syncthreads();
    for (int off = 1; off < 256; off <<= 1) {
        int v = (threadIdx.x >= off) ? s[threadIdx.x - off] : 0;
        __syncthreads();
        s[threadIdx.x] += v;
        __syncthreads();
    }
    if (i < N) rowptr[i] = part_ex[blockIdx.x] + s[threadIdx.x] - c;
    if (i == 0) rowptr[N] = E;
}

__global__ __launch_bounds__(256) void k_fill(const int* __restrict__ e, const int* __restrict__ flag,
                                              const int* __restrict__ rowptr, int* __restrict__ fill,
                                              int* __restrict__ es, int E) {
    int i = blockIdx.x * 256 + threadIdx.x;
    if (i >= E) return;
    int s = edge_at(e, flag, 0, i);
    int d = edge_at(e, flag, 1, i);
    int pos = rowptr[d] + atomicAdd(&fill[d], 1);
    es[pos] = s;
}

// Wt[col][k] = bf16(W[k][col]), zero-padded to outp cols
__global__ __launch_bounds__(256) void k_wt(const float* __restrict__ W, unsigned short* __restrict__ Wt,
                                            int outc, int outp) {
    int idx = blockIdx.x * 256 + threadIdx.x;
    if (idx >= outp * 128) return;
    int col = idx >> 7, k = idx & 127;
    Wt[idx] = (col < outc) ? f2b(W[(size_t)k * outc + col]) : (unsigned short)0;
}

// ---------------------------------------------------------------------------
// MFMA bf16 GEMM, row-major activations [N,128].
// INMODE: 0 = fp32 input, 1 = bf16 input. OUTMODE: 0 = bf16 out [N,128],
// 1 = fp32 out [N,outc] + bias. Block = 64 rows, 4 waves x 16 rows.
// LDS rows padded +8 bf16 (16B) -> 2-way bank alias only (free, m136).
// ---------------------------------------------------------------------------
template <int NT, int INMODE, int OUTMODE>
__global__ __launch_bounds__(256) void k_gemm_mfma(const void* __restrict__ Xv,
                                                   const unsigned short* __restrict__ Wt,
                                                   void* __restrict__ HoutV,
                                                   const float* __restrict__ bias, int N, int outc) {
    constexpr int OUTP = NT * 16;
    __shared__ __align__(16) unsigned short sX[64 * 136];
    __shared__ __align__(16) unsigned short sW[OUTP * 136];
    const int tid  = threadIdx.x;
    const int row0 = blockIdx.x * 64;

    if (INMODE == 0) {
        const float* X = (const float*)Xv;
        for (int c = tid; c < 64 * 16; c += 256) {
            int r = c >> 4, off = c & 15, row = row0 + r;
            unsigned short tmp[8];
            if (row < N) {
                const float* p = X + (size_t)row * 128 + off * 8;
#pragma unroll
                for (int j = 0; j < 8; ++j) tmp[j] = f2b(p[j]);
            } else {
#pragma unroll
                for (int j = 0; j < 8; ++j) tmp[j] = 0;
            }
            *(uint4*)(&sX[r * 136 + off * 8]) = *(uint4*)tmp;
        }
    } else {
        const unsigned short* X = (const unsigned short*)Xv;
        for (int c = tid; c < 64 * 16; c += 256) {
            int r = c >> 4, off = c & 15, row = row0 + r;
            uint4 v = make_uint4(0, 0, 0, 0);
            if (row < N) v = *(const uint4*)(X + (size_t)row * 128 + off * 8);
            *(uint4*)(&sX[r * 136 + off * 8]) = v;
        }
    }
    for (int c = tid; c < OUTP * 16; c += 256) {
        int r = c >> 4, off = c & 15;
        *(uint4*)(&sW[r * 136 + off * 8]) = *(const uint4*)(Wt + (size_t)r * 128 + off * 8);
    }
    __syncthreads();

    const int wave = tid >> 6, lane = tid & 63;
    const int l15 = lane & 15, g = lane >> 4;
    const int arow = (wave << 4) + l15;

    f32x4 acc[NT];
#pragma unroll
    for (int n = 0; n < NT; ++n) acc[n] = (f32x4){0.f, 0.f, 0.f, 0.f};

#pragma unroll
    for (int kk = 0; kk < 4; ++kk) {
        bf16x8 a = *(const bf16x8*)(&sX[arow * 136 + kk * 32 + g * 8]);
#pragma unroll
        for (int n = 0; n < NT; ++n) {
            bf16x8 b = *(const bf16x8*)(&sW[(n * 16 + l15) * 136 + kk * 32 + g * 8]);
            acc[n] = __builtin_amdgcn_mfma_f32_16x16x32_bf16(a, b, acc[n], 0, 0, 0);
        }
    }

    if (OUTMODE == 0) {
        unsigned short* O = (unsigned short*)HoutV;
#pragma unroll
        for (int n = 0; n < NT; ++n) {
#pragma unroll
            for (int r = 0; r < 4; ++r) {
                int row = row0 + (wave << 4) + g * 4 + r;
                if (row < N) O[(size_t)row * 128 + n * 16 + l15] = f2b(acc[n][r]);
            }
        }
    } else {
        float* O = (float*)HoutV;
#pragma unroll
        for (int n = 0; n < NT; ++n) {
            int col = n * 16 + l15;
            if (col < outc) {
                float bb = bias[col];
#pragma unroll
                for (int r = 0; r < 4; ++r) {
                    int row = row0 + (wave << 4) + g * 4 + r;
                    if (row < N) O[(size_t)row * outc + col] = acc[n][r] + bb;
                }
            }
        }
    }
}

// ---------------------------------------------------------------------------
// CSR pull, 128 bf16 features, wave per node, lane owns 2 feats.
// Latency fix vs r3: per 64-edge chunk, lane L preloads es[beg+L] and
// n_L = dis[es_L]*dd ONCE (vector loads); the inner loop broadcasts (s,n)
// via __shfl -> the per-edge chain is shfl + one coalesced 256B row gather.
// Unroll x4 keeps 4 gathers in flight. Self-loop + bias + relu fused.
// ---------------------------------------------------------------------------
template <bool RELU_BIAS>
__global__ __launch_bounds__(256) void k_pull128b(const int* __restrict__ rowptr, const int* __restrict__ es,
                                                  const float* __restrict__ dis,
                                                  const unsigned short* __restrict__ H,
                                                  const float* __restrict__ bias,
                                                  unsigned short* __restrict__ Out, int N) {
    int node = blockIdx.x * 4 + (threadIdx.x >> 6);
    if (node >= N) return;
    int   lane = threadIdx.x & 63;
    int   beg = rowptr[node], end = rowptr[node + 1];
    float dd  = dis[node];

    unsigned hv = *(const unsigned*)(H + (size_t)node * 128 + lane * 2);
    float d2 = dd * dd;
    float ax = d2 * b2f(hv & 0xffffu), ay = d2 * b2f(hv >> 16);

    for (int c = beg; c < end; c += 64) {
        int len = end - c;
        if (len > 64) len = 64;
        int   sv = es[c + (lane < len ? lane : len - 1)];
        float nv = dis[sv] * dd;

        int j = 0;
        for (; j + 4 <= len; j += 4) {
            int   s0 = __shfl(sv, j),     s1 = __shfl(sv, j + 1);
            int   s2 = __shfl(sv, j + 2), s3 = __shfl(sv, j + 3);
            float n0 = __shfl(nv, j),     n1 = __shfl(nv, j + 1);
            float n2 = __shfl(nv, j + 2), n3 = __shfl(nv, j + 3);
            unsigned u0 = *(const unsigned*)(H + (size_t)s0 * 128 + lane * 2);
            unsigned u1 = *(const unsigned*)(H + (size_t)s1 * 128 + lane * 2);
            unsigned u2 = *(const unsigned*)(H + (size_t)s2 * 128 + lane * 2);
            unsigned u3 = *(const unsigned*)(H + (size_t)s3 * 128 + lane * 2);
            ax = fmaf(b2f(u0 & 0xffffu), n0, ax);  ay = fmaf(b2f(u0 >> 16), n0, ay);
            ax = fmaf(b2f(u1 & 0xffffu), n1, ax);  ay = fmaf(b2f(u1 >> 16), n1, ay);
            ax = fmaf(b2f(u2 & 0xffffu), n2, ax);  ay = fmaf(b2f(u2 >> 16), n2, ay);
            ax = fmaf(b2f(u3 & 0xffffu), n3, ax);  ay = fmaf(b2f(u3 >> 16), n3, ay);
        }
        for (; j < len; ++j) {
            int      s0 = __shfl(sv, j);
            float    n0 = __shfl(nv, j);
            unsigned u0 = *(const unsigned*)(H + (size_t)s0 * 128 + lane * 2);
            ax = fmaf(b2f(u0 & 0xffffu), n0, ax);
            ay = fmaf(b2f(u0 >> 16), n0, ay);
        }
    }
    if (RELU_BIAS) {
        ax = fmaxf(ax + bias[lane * 2], 0.f);
        ay = fmaxf(ay + bias[lane * 2 + 1], 0.f);
    }
    unsigned o = (unsigned)f2b(ax) | ((unsigned)f2b(ay) << 16);
    *(unsigned*)(Out + (size_t)node * 128 + lane * 2) = o;
}

// log_softmax over rows of [N,40] fp32 (bias already added by GEMM epilogue)
__global__ __launch_bounds__(256) void k_lsm40(const float* __restrict__ H3, float* __restrict__ out, int N) {
    int node = blockIdx.x * 4 + (threadIdx.x >> 6);
    if (node >= N) return;
    int   lane = threadIdx.x & 63;
    float x = 0.f, m = -3.0e38f;
    if (lane < 40) { x = H3[(size_t)node * 40 + lane]; m = x; }
    for (int off = 32; off; off >>= 1) m = fmaxf(m, __shfl_xor(m, off));
    float sum = (lane < 40) ? __expf(x - m) : 0.f;
    for (int off = 32; off; off >>= 1) sum += __shfl_xor(sum, off);
    float ls = __logf(sum);
    if (lane < 40) out[(size_t)node * 40 + lane] = x - m - ls;
}

extern "C" void kernel_launch(void* const* d_in, const int* in_sizes, int n_in,
                              void* d_out, int out_size, void* d_ws, size_t ws_size,
                              hipStream_t stream) {
    const float* x   = (const float*)d_in[0];
    const int*   ei  = (const int*)d_in[1];
    const float* W1  = (const float*)d_in[2];
    const float* b1  = (const float*)d_in[3];
    const float* W2  = (const float*)d_in[4];
    const float* b2  = (const float*)d_in[5];
    const float* W3  = (const float*)d_in[6];
    const float* b3  = (const float*)d_in[7];
    float*       out = (float*)d_out;
    const int    N = N_NODES, E = N_EDGES;

    // workspace layout (bytes) — ~83 MB total
    char*           ws      = (char*)d_ws;
    int*            flag    = (int*)ws;
    int*            cnt     = (int*)(ws + 1 * (1u << 20));
    int*            fillarr = (int*)(ws + 2 * (1u << 20));
    float*          dis     = (float*)(ws + 3 * (1u << 20));
    int*            rowptr  = (int*)(ws + 4 * (1u << 20));
    int*            part    = (int*)(ws + 5 * (1u << 20));
    int*            part_ex = (int*)(ws + 5 * (1u << 20) + 65536);
    unsigned short* Wt1     = (unsigned short*)(ws + 5 * (1u << 20) + 131072);  // 32 KB
    unsigned short* Wt2     = Wt1 + 128 * 128;                                   // 32 KB
    unsigned short* Wt3     = Wt2 + 128 * 128;                                   // 12 KB
    int*            es      = (int*)(ws + 6 * (size_t)(1u << 20));               // 6.4 MB
    unsigned short* B1b     = (unsigned short*)(ws + 13 * (size_t)(1u << 20));   // 25.6 MB
    unsigned short* B2b     = (unsigned short*)(ws + 40 * (size_t)(1u << 20));   // 25.6 MB
    float*          H3      = (float*)(ws + 67 * (size_t)(1u << 20));            // 16 MB

    // ---- CSR build + weight prep ----
    k_detect<<<1, 256, 0, stream>>>(ei, flag);
    hipMemsetAsync(cnt, 0, N * sizeof(int), stream);
    hipMemsetAsync(fillarr, 0, N * sizeof(int), stream);
    k_count<<<(E + 255) / 256, 256, 0, stream>>>(ei, flag, cnt, E);
    k_dis<<<(N + 255) / 256, 256, 0, stream>>>(cnt, dis, N);
    k_scan1<<<NB_SCAN, 256, 0, stream>>>(cnt, part, N);
    k_scan2<<<1, 512, 0, stream>>>(part, part_ex, NB_SCAN);
    k_scan3<<<NB_SCAN, 256, 0, stream>>>(cnt, part_ex, rowptr, N, E);
    k_fill<<<(E + 255) / 256, 256, 0, stream>>>(ei, flag, rowptr, fillarr, es, E);
    k_wt<<<(128 * 128 + 255) / 256, 256, 0, stream>>>(W1, Wt1, 128, 128);
    k_wt<<<(128 * 128 + 255) / 256, 256, 0, stream>>>(W2, Wt2, 128, 128);
    k_wt<<<(48 * 128 + 255) / 256, 256, 0, stream>>>(W3, Wt3, 40, 48);

    const int gb = (N + 63) / 64;      // GEMM blocks
    const int pg = (N + 3) / 4;        // pull blocks

    // ---- layer 1 ----
    k_gemm_mfma<8, 0, 0><<<gb, 256, 0, stream>>>(x, Wt1, B1b, nullptr, N, 128);
    k_pull128b<true><<<pg, 256, 0, stream>>>(rowptr, es, dis, B1b, b1, B2b, N);

    // ---- layer 2 ----
    k_gemm_mfma<8, 1, 0><<<gb, 256, 0, stream>>>(B2b, Wt2, B1b, nullptr, N, 128);
    k_pull128b<true><<<pg, 256, 0, stream>>>(rowptr, es, dis, B1b, b2, B2b, N);

    // ---- layer 3: aggregate first (A and W3 commute), then GEMM + lsm ----
    k_pull128b<false><<<pg, 256, 0, stream>>>(rowptr, es, dis, B2b, nullptr, B1b, N);
    k_gemm_mfma<3, 1, 1><<<gb, 256, 0, stream>>>(B1b, Wt3, H3, b3, N, 40);
    k_lsm40<<<(N + 3) / 4, 256, 0, stream>>>(H3, out, N);
}

// Round 6
// 339.411 us; speedup vs baseline: 2.8999x; 1.3899x over previous
//
#include <hip/hip_runtime.h>
#include <cstdint>

#define N_NODES 100000
#define N_EDGES 1600000
#define F_IN 128
#define HID 128
#define N_CLS 40
#define BSHIFT 7
#define NBUCK ((N_NODES + 127) >> 7)   // 782 buckets of 128 dst nodes
#define CCHUNK 4096                     // edges per k_scatter block

typedef __attribute__((ext_vector_type(8))) short bf16x8;
typedef __attribute__((ext_vector_type(4))) float f32x4;

__device__ __forceinline__ unsigned short f2b(float f) {  // RNE f32->bf16
    unsigned u = __float_as_uint(f);
    return (unsigned short)((u + 0x7fffu + ((u >> 16) & 1u)) >> 16);
}
__device__ __forceinline__ float b2f(unsigned us) {
    return __uint_as_float(us << 16);
}

// ---------------------------------------------------------------------------
// Edge dtype detection (int64 vs int32 edge_index). Deterministic.
// ---------------------------------------------------------------------------
__global__ __launch_bounds__(256) void k_detect(const int* __restrict__ e, int* __restrict__ flag) {
    __shared__ int sor;
    if (threadIdx.x == 0) sor = 0;
    __syncthreads();
    atomicOr(&sor, e[threadIdx.x * 2 + 1]);
    __syncthreads();
    if (threadIdx.x == 0) flag[0] = (sor == 0) ? 1 : 0;  // 1 = int64 layout
}

__device__ __forceinline__ int edge_at(const int* e, const int* flag, int which, int i) {
    return flag[0] ? e[2 * ((size_t)which * N_EDGES + i)] : e[(size_t)which * N_EDGES + i];
}

// ---------------------------------------------------------------------------
// Bucketed CSR build.
// Phase A: per-bucket histogram (LDS-aggregated, coalesced reads only).
// ---------------------------------------------------------------------------
__global__ __launch_bounds__(256) void k_hist(const int* __restrict__ e, const int* __restrict__ flag,
                                              int* __restrict__ bcnt, int E) {
    __shared__ int h[NBUCK];
    for (int i = threadIdx.x; i < NBUCK; i += 256) h[i] = 0;
    __syncthreads();
    for (int i = blockIdx.x * 256 + threadIdx.x; i < E; i += gridDim.x * 256) {
        int d = edge_at(e, flag, 1, i);
        atomicAdd(&h[d >> BSHIFT], 1);
    }
    __syncthreads();
    for (int i = threadIdx.x; i < NBUCK; i += 256)
        if (h[i]) atomicAdd(&bcnt[i], h[i]);
}

// Phase B: single-block scan of bucket counts -> bucket bases + cursors.
__global__ __launch_bounds__(1024) void k_bscan(const int* __restrict__ bcnt, int* __restrict__ bbase,
                                                int* __restrict__ bcur, int E) {
    __shared__ int s0[1024], s1[1024];
    int t = threadIdx.x;
    s0[t] = (t < NBUCK) ? bcnt[t] : 0;
    __syncthreads();
    int* src = s0;
    int* dst = s1;
    for (int off = 1; off < 1024; off <<= 1) {
        dst[t] = src[t] + ((t >= off) ? src[t - off] : 0);
        __syncthreads();
        int* tmp = src; src = dst; dst = tmp;
    }
    if (t < NBUCK) {
        int ex = t ? src[t - 1] : 0;
        bbase[t] = ex;
        bcur[t]  = ex;
    }
    if (t == 0) bbase[NBUCK] = E;
}

// Phase C: LDS-binned scatter of (src,dst) pairs into bucket regions.
// Writes are slot-ordered per (block,bucket) run -> coalesced.
__global__ __launch_bounds__(256) void k_scatter(const int* __restrict__ e, const int* __restrict__ flag,
                                                 int* __restrict__ bcur, uint2* __restrict__ eb, int E) {
    __shared__ uint2 st[CCHUNK];
    __shared__ int hA[NBUCK];   // counts -> inclusive scan (ping)
    __shared__ int hB[NBUCK];   // pong -> exclusive base
    __shared__ int cur[NBUCK];
    __shared__ int runb[NBUCK];
    const int t    = threadIdx.x;
    const int base = blockIdx.x * CCHUNK;
    const int len  = min(CCHUNK, E - base);

    for (int i = t; i < NBUCK; i += 256) hA[i] = 0;
    __syncthreads();
    for (int i = t; i < len; i += 256) {
        int d = edge_at(e, flag, 1, base + i);
        atomicAdd(&hA[d >> BSHIFT], 1);
    }
    __syncthreads();
    // inclusive scan hA (ping-pong with hB), 10 steps for NBUCK<=1024
    int* src = hA;
    int* dst = hB;
    for (int off = 1; off < NBUCK; off <<= 1) {
        for (int i = t; i < NBUCK; i += 256)
            dst[i] = src[i] + ((i >= off) ? src[i - off] : 0);
        __syncthreads();
        int* tmp = src; src = dst; dst = tmp;
    }
    // src = inclusive. dst is free: write exclusive base there; init cursors; reserve runs.
    for (int i = t; i < NBUCK; i += 256) {
        int inc = src[i];
        int ex  = i ? src[i - 1] : 0;
        dst[i] = ex;
        cur[i] = ex;
        int c = inc - ex;
        if (c) runb[i] = atomicAdd(&bcur[i], c);
    }
    __syncthreads();
    // bin edges into LDS staging (bucket-grouped slot order)
    for (int i = t; i < len; i += 256) {
        int s = edge_at(e, flag, 0, base + i);
        int d = edge_at(e, flag, 1, base + i);
        int pos = atomicAdd(&cur[d >> BSHIFT], 1);
        st[pos] = make_uint2((unsigned)s, (unsigned)d);
    }
    __syncthreads();
    // coalesced copy-out: consecutive slots in a run -> consecutive addresses
    for (int i = t; i < len; i += 256) {
        uint2 v = st[i];
        int   b = (int)(v.y >> BSHIFT);
        int   gpos = runb[b] + (i - dst[b]);
        eb[gpos] = v;
    }
}

// Phase D: one block per bucket. Exact per-dst CSR within the bucket;
// fuses degree->dis and rowptr. All global writes L2-local and short-lived.
__global__ __launch_bounds__(256) void k_build(const int* __restrict__ bbase, const uint2* __restrict__ eb,
                                               int* __restrict__ rowptr, int* __restrict__ es,
                                               float* __restrict__ dis, int N, int E) {
    __shared__ int c0[128], c1[128], cur[128];
    const int b  = blockIdx.x;
    const int t  = threadIdx.x;
    const int lo = bbase[b], hi = bbase[b + 1];

    if (t < 128) c0[t] = 0;
    __syncthreads();
    for (int i = lo + t; i < hi; i += 256) atomicAdd(&c0[eb[i].y & 127], 1);
    __syncthreads();
    // inclusive scan over 128 (7 steps, ping-pong)
    int* src = c0;
    int* dst = c1;
    for (int off = 1; off < 128; off <<= 1) {
        if (t < 128) dst[t] = src[t] + ((t >= off) ? src[t - off] : 0);
        __syncthreads();
        int* tmp = src; src = dst; dst = tmp;
    }
    if (t < 128) {
        int inc = src[t], ex = t ? src[t - 1] : 0;
        int node = (b << BSHIFT) + t;
        if (node < N) {
            rowptr[node] = lo + ex;
            dis[node]    = rsqrtf((float)(inc - ex + 1));
        }
        cur[t] = ex;
    }
    if (b == 0 && t == 0) rowptr[N] = E;
    __syncthreads();
    for (int i = lo + t; i < hi; i += 256) {
        uint2 v = eb[i];
        int pos = atomicAdd(&cur[v.y & 127], 1);
        es[lo + pos] = (int)v.x;
    }
}

// Wt[col][k] = bf16(W[k][col]), zero-padded to outp cols
__global__ __launch_bounds__(256) void k_wt(const float* __restrict__ W, unsigned short* __restrict__ Wt,
                                            int outc, int outp) {
    int idx = blockIdx.x * 256 + threadIdx.x;
    if (idx >= outp * 128) return;
    int col = idx >> 7, k = idx & 127;
    Wt[idx] = (col < outc) ? f2b(W[(size_t)k * outc + col]) : (unsigned short)0;
}

// ---------------------------------------------------------------------------
// MFMA bf16 GEMM, row-major activations [N,128].
// INMODE: 0 = fp32 input, 1 = bf16 input. OUTMODE: 0 = bf16 out [N,128],
// 1 = fp32 out [N,outc] + bias. Block = 64 rows, 4 waves x 16 rows.
// LDS rows padded +8 bf16 (16B) -> 2-way bank alias only (free, m136).
// ---------------------------------------------------------------------------
template <int NT, int INMODE, int OUTMODE>
__global__ __launch_bounds__(256) void k_gemm_mfma(const void* __restrict__ Xv,
                                                   const unsigned short* __restrict__ Wt,
                                                   void* __restrict__ HoutV,
                                                   const float* __restrict__ bias, int N, int outc) {
    constexpr int OUTP = NT * 16;
    __shared__ __align__(16) unsigned short sX[64 * 136];
    __shared__ __align__(16) unsigned short sW[OUTP * 136];
    const int tid  = threadIdx.x;
    const int row0 = blockIdx.x * 64;

    if (INMODE == 0) {
        const float* X = (const float*)Xv;
        for (int c = tid; c < 64 * 16; c += 256) {
            int r = c >> 4, off = c & 15, row = row0 + r;
            unsigned short tmp[8];
            if (row < N) {
                const float* p = X + (size_t)row * 128 + off * 8;
#pragma unroll
                for (int j = 0; j < 8; ++j) tmp[j] = f2b(p[j]);
            } else {
#pragma unroll
                for (int j = 0; j < 8; ++j) tmp[j] = 0;
            }
            *(uint4*)(&sX[r * 136 + off * 8]) = *(uint4*)tmp;
        }
    } else {
        const unsigned short* X = (const unsigned short*)Xv;
        for (int c = tid; c < 64 * 16; c += 256) {
            int r = c >> 4, off = c & 15, row = row0 + r;
            uint4 v = make_uint4(0, 0, 0, 0);
            if (row < N) v = *(const uint4*)(X + (size_t)row * 128 + off * 8);
            *(uint4*)(&sX[r * 136 + off * 8]) = v;
        }
    }
    for (int c = tid; c < OUTP * 16; c += 256) {
        int r = c >> 4, off = c & 15;
        *(uint4*)(&sW[r * 136 + off * 8]) = *(const uint4*)(Wt + (size_t)r * 128 + off * 8);
    }
    __syncthreads();

    const int wave = tid >> 6, lane = tid & 63;
    const int l15 = lane & 15, g = lane >> 4;
    const int arow = (wave << 4) + l15;

    f32x4 acc[NT];
#pragma unroll
    for (int n = 0; n < NT; ++n) acc[n] = (f32x4){0.f, 0.f, 0.f, 0.f};

#pragma unroll
    for (int kk = 0; kk < 4; ++kk) {
        bf16x8 a = *(const bf16x8*)(&sX[arow * 136 + kk * 32 + g * 8]);
#pragma unroll
        for (int n = 0; n < NT; ++n) {
            bf16x8 b = *(const bf16x8*)(&sW[(n * 16 + l15) * 136 + kk * 32 + g * 8]);
            acc[n] = __builtin_amdgcn_mfma_f32_16x16x32_bf16(a, b, acc[n], 0, 0, 0);
        }
    }

    if (OUTMODE == 0) {
        unsigned short* O = (unsigned short*)HoutV;
#pragma unroll
        for (int n = 0; n < NT; ++n) {
#pragma unroll
            for (int r = 0; r < 4; ++r) {
                int row = row0 + (wave << 4) + g * 4 + r;
                if (row < N) O[(size_t)row * 128 + n * 16 + l15] = f2b(acc[n][r]);
            }
        }
    } else {
        float* O = (float*)HoutV;
#pragma unroll
        for (int n = 0; n < NT; ++n) {
            int col = n * 16 + l15;
            if (col < outc) {
                float bb = bias[col];
#pragma unroll
                for (int r = 0; r < 4; ++r) {
                    int row = row0 + (wave << 4) + g * 4 + r;
                    if (row < N) O[(size_t)row * outc + col] = acc[n][r] + bb;
                }
            }
        }
    }
}

// ---------------------------------------------------------------------------
// CSR pull, 128 bf16 features, wave per node, lane owns 2 feats.
// Per 64-edge chunk, lane L preloads es[beg+L] and n_L = dis[es_L]*dd once;
// inner loop broadcasts (s,n) via __shfl; unroll x4 keeps 4 gathers in
// flight. Self-loop + bias + relu fused.
// ---------------------------------------------------------------------------
template <bool RELU_BIAS>
__global__ __launch_bounds__(256) void k_pull128b(const int* __restrict__ rowptr, const int* __restrict__ es,
                                                  const float* __restrict__ dis,
                                                  const unsigned short* __restrict__ H,
                                                  const float* __restrict__ bias,
                                                  unsigned short* __restrict__ Out, int N) {
    int node = blockIdx.x * 4 + (threadIdx.x >> 6);
    if (node >= N) return;
    int   lane = threadIdx.x & 63;
    int   beg = rowptr[node], end = rowptr[node + 1];
    float dd  = dis[node];

    unsigned hv = *(const unsigned*)(H + (size_t)node * 128 + lane * 2);
    float d2 = dd * dd;
    float ax = d2 * b2f(hv & 0xffffu), ay = d2 * b2f(hv >> 16);

    for (int c = beg; c < end; c += 64) {
        int len = end - c;
        if (len > 64) len = 64;
        int   sv = es[c + (lane < len ? lane : len - 1)];
        float nv = dis[sv] * dd;

        int j = 0;
        for (; j + 4 <= len; j += 4) {
            int   s0 = __shfl(sv, j),     s1 = __shfl(sv, j + 1);
            int   s2 = __shfl(sv, j + 2), s3 = __shfl(sv, j + 3);
            float n0 = __shfl(nv, j),     n1 = __shfl(nv, j + 1);
            float n2 = __shfl(nv, j + 2), n3 = __shfl(nv, j + 3);
            unsigned u0 = *(const unsigned*)(H + (size_t)s0 * 128 + lane * 2);
            unsigned u1 = *(const unsigned*)(H + (size_t)s1 * 128 + lane * 2);
            unsigned u2 = *(const unsigned*)(H + (size_t)s2 * 128 + lane * 2);
            unsigned u3 = *(const unsigned*)(H + (size_t)s3 * 128 + lane * 2);
            ax = fmaf(b2f(u0 & 0xffffu), n0, ax);  ay = fmaf(b2f(u0 >> 16), n0, ay);
            ax = fmaf(b2f(u1 & 0xffffu), n1, ax);  ay = fmaf(b2f(u1 >> 16), n1, ay);
            ax = fmaf(b2f(u2 & 0xffffu), n2, ax);  ay = fmaf(b2f(u2 >> 16), n2, ay);
            ax = fmaf(b2f(u3 & 0xffffu), n3, ax);  ay = fmaf(b2f(u3 >> 16), n3, ay);
        }
        for (; j < len; ++j) {
            int      s0 = __shfl(sv, j);
            float    n0 = __shfl(nv, j);
            unsigned u0 = *(const unsigned*)(H + (size_t)s0 * 128 + lane * 2);
            ax = fmaf(b2f(u0 & 0xffffu), n0, ax);
            ay = fmaf(b2f(u0 >> 16), n0, ay);
        }
    }
    if (RELU_BIAS) {
        ax = fmaxf(ax + bias[lane * 2], 0.f);
        ay = fmaxf(ay + bias[lane * 2 + 1], 0.f);
    }
    unsigned o = (unsigned)f2b(ax) | ((unsigned)f2b(ay) << 16);
    *(unsigned*)(Out + (size_t)node * 128 + lane * 2) = o;
}

// log_softmax over rows of [N,40] fp32 (bias already added by GEMM epilogue)
__global__ __launch_bounds__(256) void k_lsm40(const float* __restrict__ H3, float* __restrict__ out, int N) {
    int node = blockIdx.x * 4 + (threadIdx.x >> 6);
    if (node >= N) return;
    int   lane = threadIdx.x & 63;
    float x = 0.f, m = -3.0e38f;
    if (lane < 40) { x = H3[(size_t)node * 40 + lane]; m = x; }
    for (int off = 32; off; off >>= 1) m = fmaxf(m, __shfl_xor(m, off));
    float sum = (lane < 40) ? __expf(x - m) : 0.f;
    for (int off = 32; off; off >>= 1) sum += __shfl_xor(sum, off);
    float ls = __logf(sum);
    if (lane < 40) out[(size_t)node * 40 + lane] = x - m - ls;
}

extern "C" void kernel_launch(void* const* d_in, const int* in_sizes, int n_in,
                              void* d_out, int out_size, void* d_ws, size_t ws_size,
                              hipStream_t stream) {
    const float* x   = (const float*)d_in[0];
    const int*   ei  = (const int*)d_in[1];
    const float* W1  = (const float*)d_in[2];
    const float* b1  = (const float*)d_in[3];
    const float* W2  = (const float*)d_in[4];
    const float* b2  = (const float*)d_in[5];
    const float* W3  = (const float*)d_in[6];
    const float* b3  = (const float*)d_in[7];
    float*       out = (float*)d_out;
    const int    N = N_NODES, E = N_EDGES;

    // workspace layout (bytes) — ~90 MB total
    char*           ws      = (char*)d_ws;
    int*            flag    = (int*)ws;                                    // 4 B
    int*            bcnt    = (int*)(ws + 4096);                           // 3.1 KB
    int*            bbase   = (int*)(ws + 16384);                          // 3.1 KB (+1)
    int*            bcur    = (int*)(ws + 32768);                          // 3.1 KB
    float*          dis     = (float*)(ws + 65536);                        // 400 KB
    int*            rowptr  = (int*)(ws + 524288);                         // 400 KB + 4
    unsigned short* Wt1     = (unsigned short*)(ws + 1 * (1u << 20));      // 32 KB
    unsigned short* Wt2     = Wt1 + 128 * 128;                             // 32 KB
    unsigned short* Wt3     = Wt2 + 128 * 128;                             // 12 KB
    uint2*          eb      = (uint2*)(ws + 2 * (size_t)(1u << 20));       // 12.8 MB
    int*            es      = (int*)(ws + 15 * (size_t)(1u << 20));        // 6.4 MB
    unsigned short* B1b     = (unsigned short*)(ws + 22 * (size_t)(1u << 20));  // 25.6 MB
    unsigned short* B2b     = (unsigned short*)(ws + 48 * (size_t)(1u << 20));  // 25.6 MB
    float*          H3      = (float*)(ws + 74 * (size_t)(1u << 20));           // 16 MB

    // ---- bucketed CSR build ----
    k_detect<<<1, 256, 0, stream>>>(ei, flag);
    hipMemsetAsync(bcnt, 0, NBUCK * sizeof(int), stream);
    k_hist<<<512, 256, 0, stream>>>(ei, flag, bcnt, E);
    k_bscan<<<1, 1024, 0, stream>>>(bcnt, bbase, bcur, E);
    k_scatter<<<(E + CCHUNK - 1) / CCHUNK, 256, 0, stream>>>(ei, flag, bcur, eb, E);
    k_build<<<NBUCK, 256, 0, stream>>>(bbase, eb, rowptr, es, dis, N, E);

    // ---- weight prep ----
    k_wt<<<(128 * 128 + 255) / 256, 256, 0, stream>>>(W1, Wt1, 128, 128);
    k_wt<<<(128 * 128 + 255) / 256, 256, 0, stream>>>(W2, Wt2, 128, 128);
    k_wt<<<(48 * 128 + 255) / 256, 256, 0, stream>>>(W3, Wt3, 40, 48);

    const int gb = (N + 63) / 64;      // GEMM blocks
    const int pg = (N + 3) / 4;        // pull blocks

    // ---- layer 1 ----
    k_gemm_mfma<8, 0, 0><<<gb, 256, 0, stream>>>(x, Wt1, B1b, nullptr, N, 128);
    k_pull128b<true><<<pg, 256, 0, stream>>>(rowptr, es, dis, B1b, b1, B2b, N);

    // ---- layer 2 ----
    k_gemm_mfma<8, 1, 0><<<gb, 256, 0, stream>>>(B2b, Wt2, B1b, nullptr, N, 128);
    k_pull128b<true><<<pg, 256, 0, stream>>>(rowptr, es, dis, B1b, b2, B2b, N);

    // ---- layer 3: aggregate first (A and W3 commute), then GEMM + lsm ----
    k_pull128b<false><<<pg, 256, 0, stream>>>(rowptr, es, dis, B2b, nullptr, B1b, N);
    k_gemm_mfma<3, 1, 1><<<gb, 256, 0, stream>>>(B1b, Wt3, H3, b3, N, 40);
    k_lsm40<<<(N + 3) / 4, 256, 0, stream>>>(H3, out, N);
}

// Round 7
// 312.699 us; speedup vs baseline: 3.1476x; 1.0854x over previous
//
#include <hip/hip_runtime.h>
#include <cstdint>

#define N_NODES 100000
#define N_EDGES 1600000
#define F_IN 128
#define HID 128
#define N_CLS 40
#define BSHIFT 7
#define NBUCK ((N_NODES + 127) >> 7)   // 782 buckets of 128 dst nodes
#define CCHUNK 4096                     // edges per scatter block
#define FUSED_LDS 52224                 // max(scatter 45280, gemm-NT8 52224)

typedef __attribute__((ext_vector_type(8))) short bf16x8;
typedef __attribute__((ext_vector_type(4))) float f32x4;

__device__ __forceinline__ unsigned short f2b(float f) {  // RNE f32->bf16
    unsigned u = __float_as_uint(f);
    return (unsigned short)((u + 0x7fffu + ((u >> 16) & 1u)) >> 16);
}
__device__ __forceinline__ float b2f(unsigned us) {
    return __uint_as_float(us << 16);
}

// ---------------------------------------------------------------------------
// Edge dtype detection (int64 vs int32 edge_index). Deterministic.
// ---------------------------------------------------------------------------
__global__ __launch_bounds__(256) void k_detect(const int* __restrict__ e, int* __restrict__ flag) {
    __shared__ int sor;
    if (threadIdx.x == 0) sor = 0;
    __syncthreads();
    atomicOr(&sor, e[threadIdx.x * 2 + 1]);
    __syncthreads();
    if (threadIdx.x == 0) flag[0] = (sor == 0) ? 1 : 0;  // 1 = int64 layout
}

__device__ __forceinline__ int edge_at(const int* e, const int* flag, int which, int i) {
    return flag[0] ? e[2 * ((size_t)which * N_EDGES + i)] : e[(size_t)which * N_EDGES + i];
}

// ---------------------------------------------------------------------------
// Bucketed CSR build. Phase A: per-bucket histogram.
// ---------------------------------------------------------------------------
__global__ __launch_bounds__(256) void k_hist(const int* __restrict__ e, const int* __restrict__ flag,
                                              int* __restrict__ bcnt, int E) {
    __shared__ int h[NBUCK];
    for (int i = threadIdx.x; i < NBUCK; i += 256) h[i] = 0;
    __syncthreads();
    for (int i = blockIdx.x * 256 + threadIdx.x; i < E; i += gridDim.x * 256) {
        int d = edge_at(e, flag, 1, i);
        atomicAdd(&h[d >> BSHIFT], 1);
    }
    __syncthreads();
    for (int i = threadIdx.x; i < NBUCK; i += 256)
        if (h[i]) atomicAdd(&bcnt[i], h[i]);
}

// Phase B: single-block scan of bucket counts -> bucket bases + cursors.
__global__ __launch_bounds__(1024) void k_bscan(const int* __restrict__ bcnt, int* __restrict__ bbase,
                                                int* __restrict__ bcur, int E) {
    __shared__ int s0[1024], s1[1024];
    int t = threadIdx.x;
    s0[t] = (t < NBUCK) ? bcnt[t] : 0;
    __syncthreads();
    int* src = s0;
    int* dst = s1;
    for (int off = 1; off < 1024; off <<= 1) {
        dst[t] = src[t] + ((t >= off) ? src[t - off] : 0);
        __syncthreads();
        int* tmp = src; src = dst; dst = tmp;
    }
    if (t < NBUCK) {
        int ex = t ? src[t - 1] : 0;
        bbase[t] = ex;
        bcur[t]  = ex;
    }
    if (t == 0) bbase[NBUCK] = E;
}

// Phase C body: LDS-binned scatter of (src,dst) pairs into bucket regions.
__device__ __forceinline__ void scatter_body(char* smem, const int* __restrict__ e,
                                             const int* __restrict__ flag, int* __restrict__ bcur,
                                             uint2* __restrict__ eb, int E, int blk) {
    uint2* st  = (uint2*)smem;              // 32768 B
    int* hA    = (int*)(smem + 32768);      // NBUCK ints each
    int* hB    = hA + NBUCK;
    int* cur   = hB + NBUCK;
    int* runb  = cur + NBUCK;
    const int t    = threadIdx.x;
    const int base = blk * CCHUNK;
    const int len  = min(CCHUNK, E - base);

    for (int i = t; i < NBUCK; i += 256) hA[i] = 0;
    __syncthreads();
    for (int i = t; i < len; i += 256) {
        int d = edge_at(e, flag, 1, base + i);
        atomicAdd(&hA[d >> BSHIFT], 1);
    }
    __syncthreads();
    int* src = hA;
    int* dst = hB;
    for (int off = 1; off < NBUCK; off <<= 1) {
        for (int i = t; i < NBUCK; i += 256)
            dst[i] = src[i] + ((i >= off) ? src[i - off] : 0);
        __syncthreads();
        int* tmp = src; src = dst; dst = tmp;
    }
    for (int i = t; i < NBUCK; i += 256) {
        int inc = src[i];
        int ex  = i ? src[i - 1] : 0;
        dst[i] = ex;
        cur[i] = ex;
        int c = inc - ex;
        if (c) runb[i] = atomicAdd(&bcur[i], c);
    }
    __syncthreads();
    for (int i = t; i < len; i += 256) {
        int s = edge_at(e, flag, 0, base + i);
        int d = edge_at(e, flag, 1, base + i);
        int pos = atomicAdd(&cur[d >> BSHIFT], 1);
        st[pos] = make_uint2((unsigned)s, (unsigned)d);
    }
    __syncthreads();
    for (int i = t; i < len; i += 256) {
        uint2 v = st[i];
        int   b = (int)(v.y >> BSHIFT);
        int   gpos = runb[b] + (i - dst[b]);
        eb[gpos] = v;
    }
}

// Phase D: one block per bucket; exact per-dst CSR; fuses degree->dis/rowptr.
__global__ __launch_bounds__(256) void k_build(const int* __restrict__ bbase, const uint2* __restrict__ eb,
                                               int* __restrict__ rowptr, int* __restrict__ es,
                                               float* __restrict__ dis, int N, int E) {
    __shared__ int c0[128], c1[128], cur[128];
    const int b  = blockIdx.x;
    const int t  = threadIdx.x;
    const int lo = bbase[b], hi = bbase[b + 1];

    if (t < 128) c0[t] = 0;
    __syncthreads();
    for (int i = lo + t; i < hi; i += 256) atomicAdd(&c0[eb[i].y & 127], 1);
    __syncthreads();
    int* src = c0;
    int* dst = c1;
    for (int off = 1; off < 128; off <<= 1) {
        if (t < 128) dst[t] = src[t] + ((t >= off) ? src[t - off] : 0);
        __syncthreads();
        int* tmp = src; src = dst; dst = tmp;
    }
    if (t < 128) {
        int inc = src[t], ex = t ? src[t - 1] : 0;
        int node = (b << BSHIFT) + t;
        if (node < N) {
            rowptr[node] = lo + ex;
            dis[node]    = rsqrtf((float)(inc - ex + 1));
        }
        cur[t] = ex;
    }
    if (b == 0 && t == 0) rowptr[N] = E;
    __syncthreads();
    for (int i = lo + t; i < hi; i += 256) {
        uint2 v = eb[i];
        int pos = atomicAdd(&cur[v.y & 127], 1);
        es[lo + pos] = (int)v.x;
    }
}

// Wt[col][k] = bf16(W[k][col]), zero-padded to outp cols
__global__ __launch_bounds__(256) void k_wt(const float* __restrict__ W, unsigned short* __restrict__ Wt,
                                            int outc, int outp) {
    int idx = blockIdx.x * 256 + threadIdx.x;
    if (idx >= outp * 128) return;
    int col = idx >> 7, k = idx & 127;
    Wt[idx] = (col < outc) ? f2b(W[(size_t)k * outc + col]) : (unsigned short)0;
}

// ---------------------------------------------------------------------------
// MFMA bf16 GEMM core. INMODE: 0 = fp32 in, 1 = bf16 in. OUTMODE: 0 = bf16
// out [N,128]; 2 = fused bias + log_softmax, fp32 out [N,outc].
// Block = 64 rows, 4 waves x 16 rows.
// ---------------------------------------------------------------------------
template <int NT, int INMODE, int OUTMODE>
__device__ __forceinline__ void gemm_core(char* smemraw, const void* __restrict__ Xv,
                                          const unsigned short* __restrict__ Wt,
                                          void* __restrict__ HoutV,
                                          const float* __restrict__ bias, int N, int outc, int blk) {
    constexpr int OUTP = NT * 16;
    unsigned short* sX = (unsigned short*)smemraw;   // 64*136
    unsigned short* sW = sX + 64 * 136;              // OUTP*136
    const int tid  = threadIdx.x;
    const int row0 = blk * 64;

    if (INMODE == 0) {
        const float* X = (const float*)Xv;
        for (int c = tid; c < 64 * 16; c += 256) {
            int r = c >> 4, off = c & 15, row = row0 + r;
            unsigned short tmp[8];
            if (row < N) {
                const float* p = X + (size_t)row * 128 + off * 8;
#pragma unroll
                for (int j = 0; j < 8; ++j) tmp[j] = f2b(p[j]);
            } else {
#pragma unroll
                for (int j = 0; j < 8; ++j) tmp[j] = 0;
            }
            *(uint4*)(&sX[r * 136 + off * 8]) = *(uint4*)tmp;
        }
    } else {
        const unsigned short* X = (const unsigned short*)Xv;
        for (int c = tid; c < 64 * 16; c += 256) {
            int r = c >> 4, off = c & 15, row = row0 + r;
            uint4 v = make_uint4(0, 0, 0, 0);
            if (row < N) v = *(const uint4*)(X + (size_t)row * 128 + off * 8);
            *(uint4*)(&sX[r * 136 + off * 8]) = v;
        }
    }
    for (int c = tid; c < OUTP * 16; c += 256) {
        int r = c >> 4, off = c & 15;
        *(uint4*)(&sW[r * 136 + off * 8]) = *(const uint4*)(Wt + (size_t)r * 128 + off * 8);
    }
    __syncthreads();

    const int wave = tid >> 6, lane = tid & 63;
    const int l15 = lane & 15, g = lane >> 4;
    const int arow = (wave << 4) + l15;

    f32x4 acc[NT];
#pragma unroll
    for (int n = 0; n < NT; ++n) acc[n] = (f32x4){0.f, 0.f, 0.f, 0.f};

#pragma unroll
    for (int kk = 0; kk < 4; ++kk) {
        bf16x8 a = *(const bf16x8*)(&sX[arow * 136 + kk * 32 + g * 8]);
#pragma unroll
        for (int n = 0; n < NT; ++n) {
            bf16x8 b = *(const bf16x8*)(&sW[(n * 16 + l15) * 136 + kk * 32 + g * 8]);
            acc[n] = __builtin_amdgcn_mfma_f32_16x16x32_bf16(a, b, acc[n], 0, 0, 0);
        }
    }

    if (OUTMODE == 0) {
        unsigned short* O = (unsigned short*)HoutV;
#pragma unroll
        for (int n = 0; n < NT; ++n) {
#pragma unroll
            for (int r = 0; r < 4; ++r) {
                int row = row0 + (wave << 4) + g * 4 + r;
                if (row < N) O[(size_t)row * 128 + n * 16 + l15] = f2b(acc[n][r]);
            }
        }
    } else {
        // fused bias + log_softmax epilogue; row's cols live in the 16 lanes
        // of this g-group (col = n*16+l15), reduce via shfl_xor 8/4/2/1.
        float* O = (float*)HoutV;
#pragma unroll
        for (int r = 0; r < 4; ++r) {
            int row = row0 + (wave << 4) + g * 4 + r;
            float v[NT];
            float m = -3.0e38f;
#pragma unroll
            for (int n = 0; n < NT; ++n) {
                int col = n * 16 + l15;
                v[n] = (col < outc) ? acc[n][r] + bias[col] : -3.0e38f;
                m = fmaxf(m, v[n]);
            }
            for (int off = 8; off; off >>= 1) m = fmaxf(m, __shfl_xor(m, off));
            float ssum = 0.f;
#pragma unroll
            for (int n = 0; n < NT; ++n) {
                int col = n * 16 + l15;
                ssum += (col < outc) ? __expf(v[n] - m) : 0.f;
            }
            for (int off = 8; off; off >>= 1) ssum += __shfl_xor(ssum, off);
            float ls = __logf(ssum);
            if (row < N) {
#pragma unroll
                for (int n = 0; n < NT; ++n) {
                    int col = n * 16 + l15;
                    if (col < outc) O[(size_t)row * outc + col] = v[n] - m - ls;
                }
            }
        }
    }
}

template <int NT, int INMODE, int OUTMODE>
__global__ __launch_bounds__(256) void k_gemm_mfma(const void* __restrict__ Xv,
                                                   const unsigned short* __restrict__ Wt,
                                                   void* __restrict__ HoutV,
                                                   const float* __restrict__ bias, int N, int outc) {
    constexpr int SZ = 64 * 136 * 2 + NT * 16 * 136 * 2;
    __shared__ __align__(16) char smem[SZ];
    gemm_core<NT, INMODE, OUTMODE>(smem, Xv, Wt, HoutV, bias, N, outc, blockIdx.x);
}

// Fused: CSR scatter (blocks [0,nscat)) || layer-1 GEMM (blocks [nscat, ...)).
__global__ __launch_bounds__(256) void k_scat_gemm1(const int* __restrict__ e, const int* __restrict__ flag,
                                                    int* __restrict__ bcur, uint2* __restrict__ eb, int E,
                                                    int nscat, const float* __restrict__ x,
                                                    const unsigned short* __restrict__ Wt1,
                                                    unsigned short* __restrict__ B1b, int N) {
    extern __shared__ __align__(16) char smem[];
    if ((int)blockIdx.x < nscat)
        scatter_body(smem, e, flag, bcur, eb, E, blockIdx.x);
    else
        gemm_core<8, 0, 0>(smem, x, Wt1, B1b, nullptr, N, 128, blockIdx.x - nscat);
}

// ---------------------------------------------------------------------------
// CSR pull, 128 bf16 features, wave per node. Lane = (edge-slot q = lane>>4,
// feat-octet f = lane&15); each uint4 load instruction gathers 4 edges' rows
// (4 x 256B). Per 64-edge chunk, lane L preloads es/dis once; (s,n) broadcast
// via per-lane __shfl (bpermute). Cross-slot reduce: shfl_xor 32/16.
// Self-loop + bias + relu fused.
// ---------------------------------------------------------------------------
#define PULL_STEP(JJ, CLAMP)                                                 \
    {                                                                        \
        int   idx = (JJ) + q;                                                \
        int   cl  = (CLAMP) ? (idx < len ? idx : len - 1) : idx;             \
        int   s   = __shfl(sv, cl);                                          \
        float n   = __shfl(nv, cl);                                          \
        if ((CLAMP) && idx >= len) n = 0.f;                                  \
        const uint4 u = *(const uint4*)(H + (size_t)s * 128 + f * 8);        \
        a0 = fmaf(b2f(u.x & 0xffffu), n, a0);                                \
        a1 = fmaf(b2f(u.x >> 16), n, a1);                                    \
        a2 = fmaf(b2f(u.y & 0xffffu), n, a2);                                \
        a3 = fmaf(b2f(u.y >> 16), n, a3);                                    \
        a4 = fmaf(b2f(u.z & 0xffffu), n, a4);                                \
        a5 = fmaf(b2f(u.z >> 16), n, a5);                                    \
        a6 = fmaf(b2f(u.w & 0xffffu), n, a6);                                \
        a7 = fmaf(b2f(u.w >> 16), n, a7);                                    \
    }

template <bool RELU_BIAS>
__global__ __launch_bounds__(256) void k_pull128c(const int* __restrict__ rowptr, const int* __restrict__ es,
                                                  const float* __restrict__ dis,
                                                  const unsigned short* __restrict__ H,
                                                  const float* __restrict__ bias,
                                                  unsigned short* __restrict__ Out, int N) {
    int node = blockIdx.x * 4 + (threadIdx.x >> 6);
    if (node >= N) return;
    const int lane = threadIdx.x & 63;
    const int q = lane >> 4, f = lane & 15;
    const int beg = rowptr[node], end = rowptr[node + 1];
    const float dd = dis[node];

    float a0 = 0.f, a1 = 0.f, a2 = 0.f, a3 = 0.f, a4 = 0.f, a5 = 0.f, a6 = 0.f, a7 = 0.f;

    for (int c = beg; c < end; c += 64) {
        int len = end - c;
        if (len > 64) len = 64;
        int   sv = es[c + (lane < len ? lane : len - 1)];
        float nv = dis[sv] * dd;

        int j = 0;
        for (; j + 8 <= len; j += 8) {
            PULL_STEP(j, false)
            PULL_STEP(j + 4, false)
        }
        for (; j < len; j += 4) PULL_STEP(j, true)
    }
    // reduce over the 4 edge slots (bits 4,5 of lane)
    a0 += __shfl_xor(a0, 32); a1 += __shfl_xor(a1, 32); a2 += __shfl_xor(a2, 32); a3 += __shfl_xor(a3, 32);
    a4 += __shfl_xor(a4, 32); a5 += __shfl_xor(a5, 32); a6 += __shfl_xor(a6, 32); a7 += __shfl_xor(a7, 32);
    a0 += __shfl_xor(a0, 16); a1 += __shfl_xor(a1, 16); a2 += __shfl_xor(a2, 16); a3 += __shfl_xor(a3, 16);
    a4 += __shfl_xor(a4, 16); a5 += __shfl_xor(a5, 16); a6 += __shfl_xor(a6, 16); a7 += __shfl_xor(a7, 16);

    if (lane < 16) {
        const uint4 u = *(const uint4*)(H + (size_t)node * 128 + lane * 8);
        const float d2 = dd * dd;
        a0 = fmaf(b2f(u.x & 0xffffu), d2, a0);
        a1 = fmaf(b2f(u.x >> 16), d2, a1);
        a2 = fmaf(b2f(u.y & 0xffffu), d2, a2);
        a3 = fmaf(b2f(u.y >> 16), d2, a3);
        a4 = fmaf(b2f(u.z & 0xffffu), d2, a4);
        a5 = fmaf(b2f(u.z >> 16), d2, a5);
        a6 = fmaf(b2f(u.w & 0xffffu), d2, a6);
        a7 = fmaf(b2f(u.w >> 16), d2, a7);
        if (RELU_BIAS) {
            const float4 bA = *(const float4*)(bias + lane * 8);
            const float4 bB = *(const float4*)(bias + lane * 8 + 4);
            a0 = fmaxf(a0 + bA.x, 0.f); a1 = fmaxf(a1 + bA.y, 0.f);
            a2 = fmaxf(a2 + bA.z, 0.f); a3 = fmaxf(a3 + bA.w, 0.f);
            a4 = fmaxf(a4 + bB.x, 0.f); a5 = fmaxf(a5 + bB.y, 0.f);
            a6 = fmaxf(a6 + bB.z, 0.f); a7 = fmaxf(a7 + bB.w, 0.f);
        }
        uint4 o;
        o.x = (unsigned)f2b(a0) | ((unsigned)f2b(a1) << 16);
        o.y = (unsigned)f2b(a2) | ((unsigned)f2b(a3) << 16);
        o.z = (unsigned)f2b(a4) | ((unsigned)f2b(a5) << 16);
        o.w = (unsigned)f2b(a6) | ((unsigned)f2b(a7) << 16);
        *(uint4*)(Out + (size_t)node * 128 + lane * 8) = o;
    }
}

extern "C" void kernel_launch(void* const* d_in, const int* in_sizes, int n_in,
                              void* d_out, int out_size, void* d_ws, size_t ws_size,
                              hipStream_t stream) {
    const float* x   = (const float*)d_in[0];
    const int*   ei  = (const int*)d_in[1];
    const float* W1  = (const float*)d_in[2];
    const float* b1  = (const float*)d_in[3];
    const float* W2  = (const float*)d_in[4];
    const float* b2  = (const float*)d_in[5];
    const float* W3  = (const float*)d_in[6];
    const float* b3  = (const float*)d_in[7];
    float*       out = (float*)d_out;
    const int    N = N_NODES, E = N_EDGES;

    // workspace layout (bytes) — ~74 MB total
    char*           ws      = (char*)d_ws;
    int*            flag    = (int*)ws;                                    // 4 B
    int*            bcnt    = (int*)(ws + 4096);
    int*            bbase   = (int*)(ws + 16384);
    int*            bcur    = (int*)(ws + 32768);
    float*          dis     = (float*)(ws + 65536);                        // 400 KB
    int*            rowptr  = (int*)(ws + 524288);                         // 400 KB + 4
    unsigned short* Wt1     = (unsigned short*)(ws + 1 * (1u << 20));      // 32 KB
    unsigned short* Wt2     = Wt1 + 128 * 128;                             // 32 KB
    unsigned short* Wt3     = Wt2 + 128 * 128;                             // 12 KB
    uint2*          eb      = (uint2*)(ws + 2 * (size_t)(1u << 20));       // 12.8 MB
    int*            es      = (int*)(ws + 15 * (size_t)(1u << 20));        // 6.4 MB
    unsigned short* B1b     = (unsigned short*)(ws + 22 * (size_t)(1u << 20));  // 25.6 MB
    unsigned short* B2b     = (unsigned short*)(ws + 48 * (size_t)(1u << 20));  // 25.6 MB

    const int nscat = (E + CCHUNK - 1) / CCHUNK;   // 391
    const int gb    = (N + 63) / 64;               // 1563
    const int pg    = (N + 3) / 4;

    // ---- CSR build + weight prep ----
    k_detect<<<1, 256, 0, stream>>>(ei, flag);
    hipMemsetAsync(bcnt, 0, NBUCK * sizeof(int), stream);
    k_wt<<<(128 * 128 + 255) / 256, 256, 0, stream>>>(W1, Wt1, 128, 128);
    k_wt<<<(128 * 128 + 255) / 256, 256, 0, stream>>>(W2, Wt2, 128, 128);
    k_wt<<<(48 * 128 + 255) / 256, 256, 0, stream>>>(W3, Wt3, 40, 48);
    k_hist<<<512, 256, 0, stream>>>(ei, flag, bcnt, E);
    k_bscan<<<1, 1024, 0, stream>>>(bcnt, bbase, bcur, E);
    // scatter || layer-1 GEMM (independent work, one launch)
    k_scat_gemm1<<<nscat + gb, 256, FUSED_LDS, stream>>>(ei, flag, bcur, eb, E, nscat, x, Wt1, B1b, N);
    k_build<<<NBUCK, 256, 0, stream>>>(bbase, eb, rowptr, es, dis, N, E);

    // ---- layer 1 aggregation ----
    k_pull128c<true><<<pg, 256, 0, stream>>>(rowptr, es, dis, B1b, b1, B2b, N);

    // ---- layer 2 ----
    k_gemm_mfma<8, 1, 0><<<gb, 256, 0, stream>>>(B2b, Wt2, B1b, nullptr, N, 128);
    k_pull128c<true><<<pg, 256, 0, stream>>>(rowptr, es, dis, B1b, b2, B2b, N);

    // ---- layer 3: aggregate first (A and W3 commute), then GEMM + fused lsm ----
    k_pull128c<false><<<pg, 256, 0, stream>>>(rowptr, es, dis, B2b, nullptr, B1b, N);
    k_gemm_mfma<3, 1, 2><<<gb, 256, 0, stream>>>(B1b, Wt3, out, b3, N, 40);
}

// Round 8
// 309.522 us; speedup vs baseline: 3.1799x; 1.0103x over previous
//
#include <hip/hip_runtime.h>
#include <hip/hip_fp16.h>
#include <cstdint>

#define N_NODES 100000
#define N_EDGES 1600000
#define F_IN 128
#define HID 128
#define N_CLS 40
#define BSHIFT 7
#define NBUCK ((N_NODES + 127) >> 7)   // 782 buckets of 128 dst nodes
#define CCHUNK 4096                     // edges per scatter block
#define FUSED_LDS 52224                 // max(scatter 45280, gemm-NT8 52224)

typedef _Float16 f16x8 __attribute__((ext_vector_type(8)));
typedef __attribute__((ext_vector_type(4))) float f32x4;

__device__ __forceinline__ unsigned short f2h(float f) {
    return __builtin_bit_cast(unsigned short, (_Float16)f);
}
__device__ __forceinline__ unsigned h2u(__half2 h) { return __builtin_bit_cast(unsigned, h); }
__device__ __forceinline__ __half2 u2h(unsigned u) { return __builtin_bit_cast(__half2, u); }

// ---------------------------------------------------------------------------
// Edge dtype detection (int64 vs int32 edge_index). Deterministic.
// ---------------------------------------------------------------------------
__global__ __launch_bounds__(256) void k_detect(const int* __restrict__ e, int* __restrict__ flag) {
    __shared__ int sor;
    if (threadIdx.x == 0) sor = 0;
    __syncthreads();
    atomicOr(&sor, e[threadIdx.x * 2 + 1]);
    __syncthreads();
    if (threadIdx.x == 0) flag[0] = (sor == 0) ? 1 : 0;  // 1 = int64 layout
}

__device__ __forceinline__ int edge_at(const int* e, const int* flag, int which, int i) {
    return flag[0] ? e[2 * ((size_t)which * N_EDGES + i)] : e[(size_t)which * N_EDGES + i];
}

// ---------------------------------------------------------------------------
// Bucketed CSR build. Phase A: per-bucket histogram.
// ---------------------------------------------------------------------------
__global__ __launch_bounds__(256) void k_hist(const int* __restrict__ e, const int* __restrict__ flag,
                                              int* __restrict__ bcnt, int E) {
    __shared__ int h[NBUCK];
    for (int i = threadIdx.x; i < NBUCK; i += 256) h[i] = 0;
    __syncthreads();
    for (int i = blockIdx.x * 256 + threadIdx.x; i < E; i += gridDim.x * 256) {
        int d = edge_at(e, flag, 1, i);
        atomicAdd(&h[d >> BSHIFT], 1);
    }
    __syncthreads();
    for (int i = threadIdx.x; i < NBUCK; i += 256)
        if (h[i]) atomicAdd(&bcnt[i], h[i]);
}

// Phase B: single-block scan of bucket counts -> bucket bases + cursors.
__global__ __launch_bounds__(1024) void k_bscan(const int* __restrict__ bcnt, int* __restrict__ bbase,
                                                int* __restrict__ bcur, int E) {
    __shared__ int s0[1024], s1[1024];
    int t = threadIdx.x;
    s0[t] = (t < NBUCK) ? bcnt[t] : 0;
    __syncthreads();
    int* src = s0;
    int* dst = s1;
    for (int off = 1; off < 1024; off <<= 1) {
        dst[t] = src[t] + ((t >= off) ? src[t - off] : 0);
        __syncthreads();
        int* tmp = src; src = dst; dst = tmp;
    }
    if (t < NBUCK) {
        int ex = t ? src[t - 1] : 0;
        bbase[t] = ex;
        bcur[t]  = ex;
    }
    if (t == 0) bbase[NBUCK] = E;
}

// Phase C body: LDS-binned scatter of (src,dst) pairs into bucket regions.
__device__ __forceinline__ void scatter_body(char* smem, const int* __restrict__ e,
                                             const int* __restrict__ flag, int* __restrict__ bcur,
                                             uint2* __restrict__ eb, int E, int blk) {
    uint2* st  = (uint2*)smem;              // 32768 B
    int* hA    = (int*)(smem + 32768);      // NBUCK ints each
    int* hB    = hA + NBUCK;
    int* cur   = hB + NBUCK;
    int* runb  = cur + NBUCK;
    const int t    = threadIdx.x;
    const int base = blk * CCHUNK;
    const int len  = min(CCHUNK, E - base);

    for (int i = t; i < NBUCK; i += 256) hA[i] = 0;
    __syncthreads();
    for (int i = t; i < len; i += 256) {
        int d = edge_at(e, flag, 1, base + i);
        atomicAdd(&hA[d >> BSHIFT], 1);
    }
    __syncthreads();
    int* src = hA;
    int* dst = hB;
    for (int off = 1; off < NBUCK; off <<= 1) {
        for (int i = t; i < NBUCK; i += 256)
            dst[i] = src[i] + ((i >= off) ? src[i - off] : 0);
        __syncthreads();
        int* tmp = src; src = dst; dst = tmp;
    }
    for (int i = t; i < NBUCK; i += 256) {
        int inc = src[i];
        int ex  = i ? src[i - 1] : 0;
        dst[i] = ex;
        cur[i] = ex;
        int c = inc - ex;
        if (c) runb[i] = atomicAdd(&bcur[i], c);
    }
    __syncthreads();
    for (int i = t; i < len; i += 256) {
        int s = edge_at(e, flag, 0, base + i);
        int d = edge_at(e, flag, 1, base + i);
        int pos = atomicAdd(&cur[d >> BSHIFT], 1);
        st[pos] = make_uint2((unsigned)s, (unsigned)d);
    }
    __syncthreads();
    for (int i = t; i < len; i += 256) {
        uint2 v = st[i];
        int   b = (int)(v.y >> BSHIFT);
        int   gpos = runb[b] + (i - dst[b]);
        eb[gpos] = v;
    }
}

// Phase D: one block per bucket; exact per-dst CSR; fuses degree->dis/rowptr.
__global__ __launch_bounds__(256) void k_build(const int* __restrict__ bbase, const uint2* __restrict__ eb,
                                               int* __restrict__ rowptr, int* __restrict__ es,
                                               float* __restrict__ dis, int N, int E) {
    __shared__ int c0[128], c1[128], cur[128];
    const int b  = blockIdx.x;
    const int t  = threadIdx.x;
    const int lo = bbase[b], hi = bbase[b + 1];

    if (t < 128) c0[t] = 0;
    __syncthreads();
    for (int i = lo + t; i < hi; i += 256) atomicAdd(&c0[eb[i].y & 127], 1);
    __syncthreads();
    int* src = c0;
    int* dst = c1;
    for (int off = 1; off < 128; off <<= 1) {
        if (t < 128) dst[t] = src[t] + ((t >= off) ? src[t - off] : 0);
        __syncthreads();
        int* tmp = src; src = dst; dst = tmp;
    }
    if (t < 128) {
        int inc = src[t], ex = t ? src[t - 1] : 0;
        int node = (b << BSHIFT) + t;
        if (node < N) {
            rowptr[node] = lo + ex;
            dis[node]    = rsqrtf((float)(inc - ex + 1));
        }
        cur[t] = ex;
    }
    if (b == 0 && t == 0) rowptr[N] = E;
    __syncthreads();
    for (int i = lo + t; i < hi; i += 256) {
        uint2 v = eb[i];
        int pos = atomicAdd(&cur[v.y & 127], 1);
        es[lo + pos] = (int)v.x;
    }
}

// Wt[col][k] = f16(W[k][col]), zero-padded to outp cols
__global__ __launch_bounds__(256) void k_wt(const float* __restrict__ W, unsigned short* __restrict__ Wt,
                                            int outc, int outp) {
    int idx = blockIdx.x * 256 + threadIdx.x;
    if (idx >= outp * 128) return;
    int col = idx >> 7, k = idx & 127;
    Wt[idx] = (col < outc) ? f2h(W[(size_t)k * outc + col]) : (unsigned short)0;
}

// ---------------------------------------------------------------------------
// MFMA f16 GEMM core. INMODE: 0 = fp32 in, 1 = f16 in. OUTMODE: 0 = f16
// out [N,128]; 2 = fused bias + log_softmax, fp32 out [N,outc].
// Block = 64 rows, 4 waves x 16 rows.
// ---------------------------------------------------------------------------
template <int NT, int INMODE, int OUTMODE>
__device__ __forceinline__ void gemm_core(char* smemraw, const void* __restrict__ Xv,
                                          const unsigned short* __restrict__ Wt,
                                          void* __restrict__ HoutV,
                                          const float* __restrict__ bias, int N, int outc, int blk) {
    constexpr int OUTP = NT * 16;
    unsigned short* sX = (unsigned short*)smemraw;   // 64*136
    unsigned short* sW = sX + 64 * 136;              // OUTP*136
    const int tid  = threadIdx.x;
    const int row0 = blk * 64;

    if (INMODE == 0) {
        const float* X = (const float*)Xv;
        for (int c = tid; c < 64 * 16; c += 256) {
            int r = c >> 4, off = c & 15, row = row0 + r;
            unsigned short tmp[8];
            if (row < N) {
                const float* p = X + (size_t)row * 128 + off * 8;
#pragma unroll
                for (int j = 0; j < 8; ++j) tmp[j] = f2h(p[j]);
            } else {
#pragma unroll
                for (int j = 0; j < 8; ++j) tmp[j] = 0;
            }
            *(uint4*)(&sX[r * 136 + off * 8]) = *(uint4*)tmp;
        }
    } else {
        const unsigned short* X = (const unsigned short*)Xv;
        for (int c = tid; c < 64 * 16; c += 256) {
            int r = c >> 4, off = c & 15, row = row0 + r;
            uint4 v = make_uint4(0, 0, 0, 0);
            if (row < N) v = *(const uint4*)(X + (size_t)row * 128 + off * 8);
            *(uint4*)(&sX[r * 136 + off * 8]) = v;
        }
    }
    for (int c = tid; c < OUTP * 16; c += 256) {
        int r = c >> 4, off = c & 15;
        *(uint4*)(&sW[r * 136 + off * 8]) = *(const uint4*)(Wt + (size_t)r * 128 + off * 8);
    }
    __syncthreads();

    const int wave = tid >> 6, lane = tid & 63;
    const int l15 = lane & 15, g = lane >> 4;
    const int arow = (wave << 4) + l15;

    f32x4 acc[NT];
#pragma unroll
    for (int n = 0; n < NT; ++n) acc[n] = (f32x4){0.f, 0.f, 0.f, 0.f};

#pragma unroll
    for (int kk = 0; kk < 4; ++kk) {
        f16x8 a = *(const f16x8*)(&sX[arow * 136 + kk * 32 + g * 8]);
#pragma unroll
        for (int n = 0; n < NT; ++n) {
            f16x8 b = *(const f16x8*)(&sW[(n * 16 + l15) * 136 + kk * 32 + g * 8]);
            acc[n] = __builtin_amdgcn_mfma_f32_16x16x32_f16(a, b, acc[n], 0, 0, 0);
        }
    }

    if (OUTMODE == 0) {
        unsigned short* O = (unsigned short*)HoutV;
#pragma unroll
        for (int n = 0; n < NT; ++n) {
#pragma unroll
            for (int r = 0; r < 4; ++r) {
                int row = row0 + (wave << 4) + g * 4 + r;
                if (row < N) O[(size_t)row * 128 + n * 16 + l15] = f2h(acc[n][r]);
            }
        }
    } else {
        // fused bias + log_softmax epilogue; row's cols live in the 16 lanes
        // of this g-group (col = n*16+l15), reduce via shfl_xor 8/4/2/1.
        float* O = (float*)HoutV;
#pragma unroll
        for (int r = 0; r < 4; ++r) {
            int row = row0 + (wave << 4) + g * 4 + r;
            float v[NT];
            float m = -3.0e38f;
#pragma unroll
            for (int n = 0; n < NT; ++n) {
                int col = n * 16 + l15;
                v[n] = (col < outc) ? acc[n][r] + bias[col] : -3.0e38f;
                m = fmaxf(m, v[n]);
            }
            for (int off = 8; off; off >>= 1) m = fmaxf(m, __shfl_xor(m, off));
            float ssum = 0.f;
#pragma unroll
            for (int n = 0; n < NT; ++n) {
                int col = n * 16 + l15;
                ssum += (col < outc) ? __expf(v[n] - m) : 0.f;
            }
            for (int off = 8; off; off >>= 1) ssum += __shfl_xor(ssum, off);
            float ls = __logf(ssum);
            if (row < N) {
#pragma unroll
                for (int n = 0; n < NT; ++n) {
                    int col = n * 16 + l15;
                    if (col < outc) O[(size_t)row * outc + col] = v[n] - m - ls;
                }
            }
        }
    }
}

template <int NT, int INMODE, int OUTMODE>
__global__ __launch_bounds__(256) void k_gemm_mfma(const void* __restrict__ Xv,
                                                   const unsigned short* __restrict__ Wt,
                                                   void* __restrict__ HoutV,
                                                   const float* __restrict__ bias, int N, int outc) {
    constexpr int SZ = 64 * 136 * 2 + NT * 16 * 136 * 2;
    __shared__ __align__(16) char smem[SZ];
    gemm_core<NT, INMODE, OUTMODE>(smem, Xv, Wt, HoutV, bias, N, outc, blockIdx.x);
}

// Fused: CSR scatter (blocks [0,nscat)) || layer-1 GEMM (blocks [nscat, ...)).
__global__ __launch_bounds__(256) void k_scat_gemm1(const int* __restrict__ e, const int* __restrict__ flag,
                                                    int* __restrict__ bcur, uint2* __restrict__ eb, int E,
                                                    int nscat, const float* __restrict__ x,
                                                    const unsigned short* __restrict__ Wt1,
                                                    unsigned short* __restrict__ B1b, int N) {
    extern __shared__ __align__(16) char smem[];
    if ((int)blockIdx.x < nscat)
        scatter_body(smem, e, flag, bcur, eb, E, blockIdx.x);
    else
        gemm_core<8, 0, 0>(smem, x, Wt1, B1b, nullptr, N, 128, blockIdx.x - nscat);
}

// ---------------------------------------------------------------------------
// CSR pull, 128 f16 features, wave per node. Lane = (edge-slot q = lane>>4,
// feat-octet f = lane&15); each uint4 load gathers 4 edges' rows. Inner MAC
// is 4 packed v_pk_fma_f16 per step (no unpack). Per 64-edge chunk, lane L
// preloads es and the half2-packed norm once; (s,n) broadcast via __shfl.
// Cross-slot reduce: packed adds over shfl_xor 32/16. Self-loop + bias +
// relu in fp32 epilogue (once per node).
// ---------------------------------------------------------------------------
#define PULL_STEP(JJ, CLAMP)                                                 \
    {                                                                        \
        int      idx = (JJ) + q;                                             \
        int      cl  = (CLAMP) ? (idx < len ? idx : 0) : idx;                \
        int      s   = __shfl(sv, cl);                                       \
        unsigned np  = (unsigned)__shfl((int)npk, cl);                       \
        if ((CLAMP) && idx >= len) np = 0u;                                  \
        const uint4 u = *(const uint4*)(H + (size_t)s * 128 + f * 8);        \
        a0 = __hfma2(u2h(u.x), u2h(np), a0);                                 \
        a1 = __hfma2(u2h(u.y), u2h(np), a1);                                 \
        a2 = __hfma2(u2h(u.z), u2h(np), a2);                                 \
        a3 = __hfma2(u2h(u.w), u2h(np), a3);                                 \
    }

#define SLOT_REDUCE(A, M)  A = __hadd2(A, u2h((unsigned)__shfl_xor((int)h2u(A), M)));

template <bool RELU_BIAS>
__global__ __launch_bounds__(256) void k_pull128h(const int* __restrict__ rowptr, const int* __restrict__ es,
                                                  const float* __restrict__ dis,
                                                  const unsigned short* __restrict__ H,
                                                  const float* __restrict__ bias,
                                                  unsigned short* __restrict__ Out, int N) {
    int node = blockIdx.x * 4 + (threadIdx.x >> 6);
    if (node >= N) return;
    const int lane = threadIdx.x & 63;
    const int q = lane >> 4, f = lane & 15;
    const int beg = rowptr[node], end = rowptr[node + 1];
    const float dd = dis[node];

    __half2 a0 = __float2half2_rn(0.f), a1 = a0, a2 = a0, a3 = a0;

    for (int c = beg; c < end; c += 64) {
        int len = end - c;
        if (len > 64) len = 64;
        int      sv  = es[c + (lane < len ? lane : len - 1)];
        unsigned npk = h2u(__float2half2_rn(dis[sv] * dd));

        int j = 0;
        for (; j + 8 <= len; j += 8) {
            PULL_STEP(j, false)
            PULL_STEP(j + 4, false)
        }
        for (; j < len; j += 4) PULL_STEP(j, true)
    }
    // reduce over the 4 edge slots (bits 4,5 of lane), packed
    SLOT_REDUCE(a0, 32) SLOT_REDUCE(a1, 32) SLOT_REDUCE(a2, 32) SLOT_REDUCE(a3, 32)
    SLOT_REDUCE(a0, 16) SLOT_REDUCE(a1, 16) SLOT_REDUCE(a2, 16) SLOT_REDUCE(a3, 16)

    if (lane < 16) {
        float r0 = __low2float(a0), r1 = __high2float(a0);
        float r2 = __low2float(a1), r3 = __high2float(a1);
        float r4 = __low2float(a2), r5 = __high2float(a2);
        float r6 = __low2float(a3), r7 = __high2float(a3);
        // self-loop term in fp32
        const uint4 u  = *(const uint4*)(H + (size_t)node * 128 + lane * 8);
        const float d2 = dd * dd;
        r0 = fmaf(__low2float(u2h(u.x)), d2, r0);  r1 = fmaf(__high2float(u2h(u.x)), d2, r1);
        r2 = fmaf(__low2float(u2h(u.y)), d2, r2);  r3 = fmaf(__high2float(u2h(u.y)), d2, r3);
        r4 = fmaf(__low2float(u2h(u.z)), d2, r4);  r5 = fmaf(__high2float(u2h(u.z)), d2, r5);
        r6 = fmaf(__low2float(u2h(u.w)), d2, r6);  r7 = fmaf(__high2float(u2h(u.w)), d2, r7);
        if (RELU_BIAS) {
            const float4 bA = *(const float4*)(bias + lane * 8);
            const float4 bB = *(const float4*)(bias + lane * 8 + 4);
            r0 = fmaxf(r0 + bA.x, 0.f); r1 = fmaxf(r1 + bA.y, 0.f);
            r2 = fmaxf(r2 + bA.z, 0.f); r3 = fmaxf(r3 + bA.w, 0.f);
            r4 = fmaxf(r4 + bB.x, 0.f); r5 = fmaxf(r5 + bB.y, 0.f);
            r6 = fmaxf(r6 + bB.z, 0.f); r7 = fmaxf(r7 + bB.w, 0.f);
        }
        uint4 o;
        o.x = (unsigned)f2h(r0) | ((unsigned)f2h(r1) << 16);
        o.y = (unsigned)f2h(r2) | ((unsigned)f2h(r3) << 16);
        o.z = (unsigned)f2h(r4) | ((unsigned)f2h(r5) << 16);
        o.w = (unsigned)f2h(r6) | ((unsigned)f2h(r7) << 16);
        *(uint4*)(Out + (size_t)node * 128 + lane * 8) = o;
    }
}

extern "C" void kernel_launch(void* const* d_in, const int* in_sizes, int n_in,
                              void* d_out, int out_size, void* d_ws, size_t ws_size,
                              hipStream_t stream) {
    const float* x   = (const float*)d_in[0];
    const int*   ei  = (const int*)d_in[1];
    const float* W1  = (const float*)d_in[2];
    const float* b1  = (const float*)d_in[3];
    const float* W2  = (const float*)d_in[4];
    const float* b2  = (const float*)d_in[5];
    const float* W3  = (const float*)d_in[6];
    const float* b3  = (const float*)d_in[7];
    float*       out = (float*)d_out;
    const int    N = N_NODES, E = N_EDGES;

    // workspace layout (bytes) — ~74 MB total
    char*           ws      = (char*)d_ws;
    int*            flag    = (int*)ws;                                    // 4 B
    int*            bcnt    = (int*)(ws + 4096);
    int*            bbase   = (int*)(ws + 16384);
    int*            bcur    = (int*)(ws + 32768);
    float*          dis     = (float*)(ws + 65536);                        // 400 KB
    int*            rowptr  = (int*)(ws + 524288);                         // 400 KB + 4
    unsigned short* Wt1     = (unsigned short*)(ws + 1 * (1u << 20));      // 32 KB
    unsigned short* Wt2     = Wt1 + 128 * 128;                             // 32 KB
    unsigned short* Wt3     = Wt2 + 128 * 128;                             // 12 KB
    uint2*          eb      = (uint2*)(ws + 2 * (size_t)(1u << 20));       // 12.8 MB
    int*            es      = (int*)(ws + 15 * (size_t)(1u << 20));        // 6.4 MB
    unsigned short* B1b     = (unsigned short*)(ws + 22 * (size_t)(1u << 20));  // 25.6 MB
    unsigned short* B2b     = (unsigned short*)(ws + 48 * (size_t)(1u << 20));  // 25.6 MB

    const int nscat = (E + CCHUNK - 1) / CCHUNK;   // 391
    const int gb    = (N + 63) / 64;               // 1563
    const int pg    = (N + 3) / 4;

    // ---- CSR build + weight prep ----
    k_detect<<<1, 256, 0, stream>>>(ei, flag);
    hipMemsetAsync(bcnt, 0, NBUCK * sizeof(int), stream);
    k_wt<<<(128 * 128 + 255) / 256, 256, 0, stream>>>(W1, Wt1, 128, 128);
    k_wt<<<(128 * 128 + 255) / 256, 256, 0, stream>>>(W2, Wt2, 128, 128);
    k_wt<<<(48 * 128 + 255) / 256, 256, 0, stream>>>(W3, Wt3, 40, 48);
    k_hist<<<512, 256, 0, stream>>>(ei, flag, bcnt, E);
    k_bscan<<<1, 1024, 0, stream>>>(bcnt, bbase, bcur, E);
    // scatter || layer-1 GEMM (independent work, one launch)
    k_scat_gemm1<<<nscat + gb, 256, FUSED_LDS, stream>>>(ei, flag, bcur, eb, E, nscat, x, Wt1, B1b, N);
    k_build<<<NBUCK, 256, 0, stream>>>(bbase, eb, rowptr, es, dis, N, E);

    // ---- layer 1 aggregation ----
    k_pull128h<true><<<pg, 256, 0, stream>>>(rowptr, es, dis, B1b, b1, B2b, N);

    // ---- layer 2 ----
    k_gemm_mfma<8, 1, 0><<<gb, 256, 0, stream>>>(B2b, Wt2, B1b, nullptr, N, 128);
    k_pull128h<true><<<pg, 256, 0, stream>>>(rowptr, es, dis, B1b, b2, B2b, N);

    // ---- layer 3: aggregate first (A and W3 commute), then GEMM + fused lsm ----
    k_pull128h<false><<<pg, 256, 0, stream>>>(rowptr, es, dis, B2b, nullptr, B1b, N);
    k_gemm_mfma<3, 1, 2><<<gb, 256, 0, stream>>>(B1b, Wt3, out, b3, N, 40);
}

// Round 9
// 273.860 us; speedup vs baseline: 3.5940x; 1.1302x over previous
//
#include <hip/hip_runtime.h>
#include <hip/hip_fp16.h>
#include <cstdint>

#define N_NODES 100000
#define N_EDGES 1600000
#define F_IN 128
#define HID 128
#define N_CLS 40
#define BSHIFT 7
#define NBUCK ((N_NODES + 127) >> 7)   // 782 buckets of 128 dst nodes
#define CCHUNK 4096                     // edges per scatter block
#define FUSED_LDS 52224                 // max(scatter 45280, gemm-NT8 52224)

typedef _Float16 f16x8 __attribute__((ext_vector_type(8)));
typedef __attribute__((ext_vector_type(4))) float f32x4;
typedef __attribute__((ext_vector_type(2))) float f32x2;

__device__ __forceinline__ unsigned short f2h(float f) {
    return __builtin_bit_cast(unsigned short, (_Float16)f);
}
__device__ __forceinline__ __half2 u2h(unsigned u) { return __builtin_bit_cast(__half2, u); }

// fp8 (OCP e4m3 on gfx950) pack/unpack via HW converts
__device__ __forceinline__ f32x2 fp8_lo(unsigned u) { return __builtin_amdgcn_cvt_pk_f32_fp8((int)u, false); }
__device__ __forceinline__ f32x2 fp8_hi(unsigned u) { return __builtin_amdgcn_cvt_pk_f32_fp8((int)u, true); }
__device__ __forceinline__ unsigned char f2e(float v) {
    return (unsigned char)(__builtin_amdgcn_cvt_pk_fp8_f32(v, v, 0, false) & 0xff);
}

// ---------------------------------------------------------------------------
// Edge dtype detection (int64 vs int32 edge_index). Deterministic.
// ---------------------------------------------------------------------------
__global__ __launch_bounds__(256) void k_detect(const int* __restrict__ e, int* __restrict__ flag) {
    __shared__ int sor;
    if (threadIdx.x == 0) sor = 0;
    __syncthreads();
    atomicOr(&sor, e[threadIdx.x * 2 + 1]);
    __syncthreads();
    if (threadIdx.x == 0) flag[0] = (sor == 0) ? 1 : 0;  // 1 = int64 layout
}

__device__ __forceinline__ int edge_at(const int* e, const int* flag, int which, int i) {
    return flag[0] ? e[2 * ((size_t)which * N_EDGES + i)] : e[(size_t)which * N_EDGES + i];
}

// ---------------------------------------------------------------------------
// Bucketed CSR build. Phase A: per-bucket histogram.
// ---------------------------------------------------------------------------
__global__ __launch_bounds__(256) void k_hist(const int* __restrict__ e, const int* __restrict__ flag,
                                              int* __restrict__ bcnt, int E) {
    __shared__ int h[NBUCK];
    for (int i = threadIdx.x; i < NBUCK; i += 256) h[i] = 0;
    __syncthreads();
    for (int i = blockIdx.x * 256 + threadIdx.x; i < E; i += gridDim.x * 256) {
        int d = edge_at(e, flag, 1, i);
        atomicAdd(&h[d >> BSHIFT], 1);
    }
    __syncthreads();
    for (int i = threadIdx.x; i < NBUCK; i += 256)
        if (h[i]) atomicAdd(&bcnt[i], h[i]);
}

// Phase B: single-block scan of bucket counts -> bucket bases + cursors.
__global__ __launch_bounds__(1024) void k_bscan(const int* __restrict__ bcnt, int* __restrict__ bbase,
                                                int* __restrict__ bcur, int E) {
    __shared__ int s0[1024], s1[1024];
    int t = threadIdx.x;
    s0[t] = (t < NBUCK) ? bcnt[t] : 0;
    __syncthreads();
    int* src = s0;
    int* dst = s1;
    for (int off = 1; off < 1024; off <<= 1) {
        dst[t] = src[t] + ((t >= off) ? src[t - off] : 0);
        __syncthreads();
        int* tmp = src; src = dst; dst = tmp;
    }
    if (t < NBUCK) {
        int ex = t ? src[t - 1] : 0;
        bbase[t] = ex;
        bcur[t]  = ex;
    }
    if (t == 0) bbase[NBUCK] = E;
}

// Phase C body: LDS-binned scatter of (src,dst) pairs into bucket regions.
__device__ __forceinline__ void scatter_body(char* smem, const int* __restrict__ e,
                                             const int* __restrict__ flag, int* __restrict__ bcur,
                                             uint2* __restrict__ eb, int E, int blk) {
    uint2* st  = (uint2*)smem;              // 32768 B
    int* hA    = (int*)(smem + 32768);      // NBUCK ints each
    int* hB    = hA + NBUCK;
    int* cur   = hB + NBUCK;
    int* runb  = cur + NBUCK;
    const int t    = threadIdx.x;
    const int base = blk * CCHUNK;
    const int len  = min(CCHUNK, E - base);

    for (int i = t; i < NBUCK; i += 256) hA[i] = 0;
    __syncthreads();
    for (int i = t; i < len; i += 256) {
        int d = edge_at(e, flag, 1, base + i);
        atomicAdd(&hA[d >> BSHIFT], 1);
    }
    __syncthreads();
    int* src = hA;
    int* dst = hB;
    for (int off = 1; off < NBUCK; off <<= 1) {
        for (int i = t; i < NBUCK; i += 256)
            dst[i] = src[i] + ((i >= off) ? src[i - off] : 0);
        __syncthreads();
        int* tmp = src; src = dst; dst = tmp;
    }
    for (int i = t; i < NBUCK; i += 256) {
        int inc = src[i];
        int ex  = i ? src[i - 1] : 0;
        dst[i] = ex;
        cur[i] = ex;
        int c = inc - ex;
        if (c) runb[i] = atomicAdd(&bcur[i], c);
    }
    __syncthreads();
    for (int i = t; i < len; i += 256) {
        int s = edge_at(e, flag, 0, base + i);
        int d = edge_at(e, flag, 1, base + i);
        int pos = atomicAdd(&cur[d >> BSHIFT], 1);
        st[pos] = make_uint2((unsigned)s, (unsigned)d);
    }
    __syncthreads();
    for (int i = t; i < len; i += 256) {
        uint2 v = st[i];
        int   b = (int)(v.y >> BSHIFT);
        int   gpos = runb[b] + (i - dst[b]);
        eb[gpos] = v;
    }
}

// Phase D: one block per bucket; exact per-dst CSR; fuses degree->dis/rowptr.
__global__ __launch_bounds__(256) void k_build(const int* __restrict__ bbase, const uint2* __restrict__ eb,
                                               int* __restrict__ rowptr, int* __restrict__ es,
                                               float* __restrict__ dis, int N, int E) {
    __shared__ int c0[128], c1[128], cur[128];
    const int b  = blockIdx.x;
    const int t  = threadIdx.x;
    const int lo = bbase[b], hi = bbase[b + 1];

    if (t < 128) c0[t] = 0;
    __syncthreads();
    for (int i = lo + t; i < hi; i += 256) atomicAdd(&c0[eb[i].y & 127], 1);
    __syncthreads();
    int* src = c0;
    int* dst = c1;
    for (int off = 1; off < 128; off <<= 1) {
        if (t < 128) dst[t] = src[t] + ((t >= off) ? src[t - off] : 0);
        __syncthreads();
        int* tmp = src; src = dst; dst = tmp;
    }
    if (t < 128) {
        int inc = src[t], ex = t ? src[t - 1] : 0;
        int node = (b << BSHIFT) + t;
        if (node < N) {
            rowptr[node] = lo + ex;
            dis[node]    = rsqrtf((float)(inc - ex + 1));
        }
        cur[t] = ex;
    }
    if (b == 0 && t == 0) rowptr[N] = E;
    __syncthreads();
    for (int i = lo + t; i < hi; i += 256) {
        uint2 v = eb[i];
        int pos = atomicAdd(&cur[v.y & 127], 1);
        es[lo + pos] = (int)v.x;
    }
}

// Wt[col][k] = f16(W[k][col]), zero-padded to outp cols
__global__ __launch_bounds__(256) void k_wt(const float* __restrict__ W, unsigned short* __restrict__ Wt,
                                            int outc, int outp) {
    int idx = blockIdx.x * 256 + threadIdx.x;
    if (idx >= outp * 128) return;
    int col = idx >> 7, k = idx & 127;
    Wt[idx] = (col < outc) ? f2h(W[(size_t)k * outc + col]) : (unsigned short)0;
}

// ---------------------------------------------------------------------------
// MFMA f16 GEMM core. INMODE: 0 = fp32 in, 1 = f16 in. OUTMODE: 0 = f16 out
// [N,128] + fp8 copy (for the next pull's gather); 2 = fused bias +
// log_softmax, fp32 out [N,outc]. Block = 64 rows, 4 waves x 16 rows.
// ---------------------------------------------------------------------------
template <int NT, int INMODE, int OUTMODE>
__device__ __forceinline__ void gemm_core(char* smemraw, const void* __restrict__ Xv,
                                          const unsigned short* __restrict__ Wt,
                                          void* __restrict__ HoutV, unsigned char* __restrict__ O8,
                                          const float* __restrict__ bias, int N, int outc, int blk) {
    constexpr int OUTP = NT * 16;
    unsigned short* sX = (unsigned short*)smemraw;   // 64*136
    unsigned short* sW = sX + 64 * 136;              // OUTP*136
    const int tid  = threadIdx.x;
    const int row0 = blk * 64;

    if (INMODE == 0) {
        const float* X = (const float*)Xv;
        for (int c = tid; c < 64 * 16; c += 256) {
            int r = c >> 4, off = c & 15, row = row0 + r;
            unsigned short tmp[8];
            if (row < N) {
                const float* p = X + (size_t)row * 128 + off * 8;
#pragma unroll
                for (int j = 0; j < 8; ++j) tmp[j] = f2h(p[j]);
            } else {
#pragma unroll
                for (int j = 0; j < 8; ++j) tmp[j] = 0;
            }
            *(uint4*)(&sX[r * 136 + off * 8]) = *(uint4*)tmp;
        }
    } else {
        const unsigned short* X = (const unsigned short*)Xv;
        for (int c = tid; c < 64 * 16; c += 256) {
            int r = c >> 4, off = c & 15, row = row0 + r;
            uint4 v = make_uint4(0, 0, 0, 0);
            if (row < N) v = *(const uint4*)(X + (size_t)row * 128 + off * 8);
            *(uint4*)(&sX[r * 136 + off * 8]) = v;
        }
    }
    for (int c = tid; c < OUTP * 16; c += 256) {
        int r = c >> 4, off = c & 15;
        *(uint4*)(&sW[r * 136 + off * 8]) = *(const uint4*)(Wt + (size_t)r * 128 + off * 8);
    }
    __syncthreads();

    const int wave = tid >> 6, lane = tid & 63;
    const int l15 = lane & 15, g = lane >> 4;
    const int arow = (wave << 4) + l15;

    f32x4 acc[NT];
#pragma unroll
    for (int n = 0; n < NT; ++n) acc[n] = (f32x4){0.f, 0.f, 0.f, 0.f};

#pragma unroll
    for (int kk = 0; kk < 4; ++kk) {
        f16x8 a = *(const f16x8*)(&sX[arow * 136 + kk * 32 + g * 8]);
#pragma unroll
        for (int n = 0; n < NT; ++n) {
            f16x8 b = *(const f16x8*)(&sW[(n * 16 + l15) * 136 + kk * 32 + g * 8]);
            acc[n] = __builtin_amdgcn_mfma_f32_16x16x32_f16(a, b, acc[n], 0, 0, 0);
        }
    }

    if (OUTMODE == 0) {
        unsigned short* O = (unsigned short*)HoutV;
#pragma unroll
        for (int n = 0; n < NT; ++n) {
#pragma unroll
            for (int r = 0; r < 4; ++r) {
                int row = row0 + (wave << 4) + g * 4 + r;
                if (row < N) {
                    O[(size_t)row * 128 + n * 16 + l15]  = f2h(acc[n][r]);
                    O8[(size_t)row * 128 + n * 16 + l15] = f2e(acc[n][r]);
                }
            }
        }
    } else {
        // fused bias + log_softmax epilogue; row's cols live in the 16 lanes
        // of this g-group (col = n*16+l15), reduce via shfl_xor 8/4/2/1.
        float* O = (float*)HoutV;
#pragma unroll
        for (int r = 0; r < 4; ++r) {
            int row = row0 + (wave << 4) + g * 4 + r;
            float v[NT];
            float m = -3.0e38f;
#pragma unroll
            for (int n = 0; n < NT; ++n) {
                int col = n * 16 + l15;
                v[n] = (col < outc) ? acc[n][r] + bias[col] : -3.0e38f;
                m = fmaxf(m, v[n]);
            }
            for (int off = 8; off; off >>= 1) m = fmaxf(m, __shfl_xor(m, off));
            float ssum = 0.f;
#pragma unroll
            for (int n = 0; n < NT; ++n) {
                int col = n * 16 + l15;
                ssum += (col < outc) ? __expf(v[n] - m) : 0.f;
            }
            for (int off = 8; off; off >>= 1) ssum += __shfl_xor(ssum, off);
            float ls = __logf(ssum);
            if (row < N) {
#pragma unroll
                for (int n = 0; n < NT; ++n) {
                    int col = n * 16 + l15;
                    if (col < outc) O[(size_t)row * outc + col] = v[n] - m - ls;
                }
            }
        }
    }
}

template <int NT, int INMODE, int OUTMODE>
__global__ __launch_bounds__(256) void k_gemm_mfma(const void* __restrict__ Xv,
                                                   const unsigned short* __restrict__ Wt,
                                                   void* __restrict__ HoutV, unsigned char* __restrict__ O8,
                                                   const float* __restrict__ bias, int N, int outc) {
    constexpr int SZ = 64 * 136 * 2 + NT * 16 * 136 * 2;
    __shared__ __align__(16) char smem[SZ];
    gemm_core<NT, INMODE, OUTMODE>(smem, Xv, Wt, HoutV, O8, bias, N, outc, blockIdx.x);
}

// Fused: CSR scatter (blocks [0,nscat)) || layer-1 GEMM (blocks [nscat, ...)).
__global__ __launch_bounds__(256) void k_scat_gemm1(const int* __restrict__ e, const int* __restrict__ flag,
                                                    int* __restrict__ bcur, uint2* __restrict__ eb, int E,
                                                    int nscat, const float* __restrict__ x,
                                                    const unsigned short* __restrict__ Wt1,
                                                    unsigned short* __restrict__ B1b,
                                                    unsigned char* __restrict__ B1e, int N) {
    extern __shared__ __align__(16) char smem[];
    if ((int)blockIdx.x < nscat)
        scatter_body(smem, e, flag, bcur, eb, E, blockIdx.x);
    else
        gemm_core<8, 0, 0>(smem, x, Wt1, B1b, B1e, nullptr, N, 128, blockIdx.x - nscat);
}

// ---------------------------------------------------------------------------
// CSR pull: gather fp8 rows (128B), accumulate f32x2 (packed), self-loop from
// the f16 copy, epilogue writes f16 (uint4) + optional fp8 (uint2) copies.
// Lane = (edge-slot q = lane>>4, feat-octet f = lane&15); one uint2 load
// gathers 4 edges' rows. Per 64-edge chunk lane L preloads es + norm once;
// (s,n) broadcast via __shfl. Cross-slot reduce: shfl_xor 32/16.
// ---------------------------------------------------------------------------
#define PULL_STEP(JJ, CLAMP)                                                 \
    {                                                                        \
        int   idx = (JJ) + q;                                                \
        int   cl  = (CLAMP) ? (idx < len ? idx : 0) : idx;                   \
        int   s   = __shfl(sv, cl);                                          \
        float n   = __shfl(nv, cl);                                          \
        if ((CLAMP) && idx >= len) n = 0.f;                                  \
        const uint2 u  = *(const uint2*)(H8 + (size_t)s * 128 + f * 8);      \
        const f32x2 nn = {n, n};                                             \
        a0 += fp8_lo(u.x) * nn;                                              \
        a1 += fp8_hi(u.x) * nn;                                              \
        a2 += fp8_lo(u.y) * nn;                                              \
        a3 += fp8_hi(u.y) * nn;                                              \
    }

#define SLOT_REDUCE(A, M) { A.x += __shfl_xor(A.x, M); A.y += __shfl_xor(A.y, M); }

template <bool RELU_BIAS, bool W8>
__global__ __launch_bounds__(256) void k_pull128e(const int* __restrict__ rowptr, const int* __restrict__ es,
                                                  const float* __restrict__ dis,
                                                  const unsigned char* __restrict__ H8,
                                                  const unsigned short* __restrict__ Hf,
                                                  const float* __restrict__ bias,
                                                  unsigned short* __restrict__ Outf,
                                                  unsigned char* __restrict__ Out8, int N) {
    int node = blockIdx.x * 4 + (threadIdx.x >> 6);
    if (node >= N) return;
    const int lane = threadIdx.x & 63;
    const int q = lane >> 4, f = lane & 15;
    const int beg = rowptr[node], end = rowptr[node + 1];
    const float dd = dis[node];

    f32x2 a0 = {0.f, 0.f}, a1 = a0, a2 = a0, a3 = a0;

    for (int c = beg; c < end; c += 64) {
        int len = end - c;
        if (len > 64) len = 64;
        int   sv = es[c + (lane < len ? lane : len - 1)];
        float nv = dis[sv] * dd;

        int j = 0;
        for (; j + 8 <= len; j += 8) {
            PULL_STEP(j, false)
            PULL_STEP(j + 4, false)
        }
        for (; j < len; j += 4) PULL_STEP(j, true)
    }
    // reduce over the 4 edge slots (bits 4,5 of lane)
    SLOT_REDUCE(a0, 32) SLOT_REDUCE(a1, 32) SLOT_REDUCE(a2, 32) SLOT_REDUCE(a3, 32)
    SLOT_REDUCE(a0, 16) SLOT_REDUCE(a1, 16) SLOT_REDUCE(a2, 16) SLOT_REDUCE(a3, 16)

    if (lane < 16) {
        float r0 = a0.x, r1 = a0.y, r2 = a1.x, r3 = a1.y;
        float r4 = a2.x, r5 = a2.y, r6 = a3.x, r7 = a3.y;
        // self-loop term from the f16 copy (full precision path)
        const uint4 u  = *(const uint4*)(Hf + (size_t)node * 128 + lane * 8);
        const float d2 = dd * dd;
        r0 = fmaf(__low2float(u2h(u.x)), d2, r0);  r1 = fmaf(__high2float(u2h(u.x)), d2, r1);
        r2 = fmaf(__low2float(u2h(u.y)), d2, r2);  r3 = fmaf(__high2float(u2h(u.y)), d2, r3);
        r4 = fmaf(__low2float(u2h(u.z)), d2, r4);  r5 = fmaf(__high2float(u2h(u.z)), d2, r5);
        r6 = fmaf(__low2float(u2h(u.w)), d2, r6);  r7 = fmaf(__high2float(u2h(u.w)), d2, r7);
        if (RELU_BIAS) {
            const float4 bA = *(const float4*)(bias + lane * 8);
            const float4 bB = *(const float4*)(bias + lane * 8 + 4);
            r0 = fmaxf(r0 + bA.x, 0.f); r1 = fmaxf(r1 + bA.y, 0.f);
            r2 = fmaxf(r2 + bA.z, 0.f); r3 = fmaxf(r3 + bA.w, 0.f);
            r4 = fmaxf(r4 + bB.x, 0.f); r5 = fmaxf(r5 + bB.y, 0.f);
            r6 = fmaxf(r6 + bB.z, 0.f); r7 = fmaxf(r7 + bB.w, 0.f);
        }
        uint4 o;
        o.x = (unsigned)f2h(r0) | ((unsigned)f2h(r1) << 16);
        o.y = (unsigned)f2h(r2) | ((unsigned)f2h(r3) << 16);
        o.z = (unsigned)f2h(r4) | ((unsigned)f2h(r5) << 16);
        o.w = (unsigned)f2h(r6) | ((unsigned)f2h(r7) << 16);
        *(uint4*)(Outf + (size_t)node * 128 + lane * 8) = o;
        if (W8) {
            int w0 = __builtin_amdgcn_cvt_pk_fp8_f32(r0, r1, 0, false);
            w0     = __builtin_amdgcn_cvt_pk_fp8_f32(r2, r3, w0, true);
            int w1 = __builtin_amdgcn_cvt_pk_fp8_f32(r4, r5, 0, false);
            w1     = __builtin_amdgcn_cvt_pk_fp8_f32(r6, r7, w1, true);
            *(uint2*)(Out8 + (size_t)node * 128 + lane * 8) = make_uint2((unsigned)w0, (unsigned)w1);
        }
    }
}

extern "C" void kernel_launch(void* const* d_in, const int* in_sizes, int n_in,
                              void* d_out, int out_size, void* d_ws, size_t ws_size,
                              hipStream_t stream) {
    const float* x   = (const float*)d_in[0];
    const int*   ei  = (const int*)d_in[1];
    const float* W1  = (const float*)d_in[2];
    const float* b1  = (const float*)d_in[3];
    const float* W2  = (const float*)d_in[4];
    const float* b2  = (const float*)d_in[5];
    const float* W3  = (const float*)d_in[6];
    const float* b3  = (const float*)d_in[7];
    float*       out = (float*)d_out;
    const int    N = N_NODES, E = N_EDGES;

    // workspace layout (bytes) — ~100 MB total
    char*           ws      = (char*)d_ws;
    int*            flag    = (int*)ws;                                    // 4 B
    int*            bcnt    = (int*)(ws + 4096);
    int*            bbase   = (int*)(ws + 16384);
    int*            bcur    = (int*)(ws + 32768);
    float*          dis     = (float*)(ws + 65536);                        // 400 KB
    int*            rowptr  = (int*)(ws + 524288);                         // 400 KB + 4
    unsigned short* Wt1     = (unsigned short*)(ws + 1 * (1u << 20));      // 32 KB
    unsigned short* Wt2     = Wt1 + 128 * 128;                             // 32 KB
    unsigned short* Wt3     = Wt2 + 128 * 128;                             // 12 KB
    uint2*          eb      = (uint2*)(ws + 2 * (size_t)(1u << 20));       // 12.8 MB
    int*            es      = (int*)(ws + 15 * (size_t)(1u << 20));        // 6.4 MB
    unsigned short* B1b     = (unsigned short*)(ws + 22 * (size_t)(1u << 20));  // 25.6 MB (f16)
    unsigned short* B2b     = (unsigned short*)(ws + 48 * (size_t)(1u << 20));  // 25.6 MB (f16)
    unsigned char*  B1e     = (unsigned char*)(ws + 74 * (size_t)(1u << 20));   // 12.8 MB (fp8)
    unsigned char*  B2e     = (unsigned char*)(ws + 87 * (size_t)(1u << 20));   // 12.8 MB (fp8)

    const int nscat = (E + CCHUNK - 1) / CCHUNK;   // 391
    const int gb    = (N + 63) / 64;               // 1563
    const int pg    = (N + 3) / 4;

    // ---- CSR build + weight prep ----
    k_detect<<<1, 256, 0, stream>>>(ei, flag);
    hipMemsetAsync(bcnt, 0, NBUCK * sizeof(int), stream);
    k_wt<<<(128 * 128 + 255) / 256, 256, 0, stream>>>(W1, Wt1, 128, 128);
    k_wt<<<(128 * 128 + 255) / 256, 256, 0, stream>>>(W2, Wt2, 128, 128);
    k_wt<<<(48 * 128 + 255) / 256, 256, 0, stream>>>(W3, Wt3, 40, 48);
    k_hist<<<512, 256, 0, stream>>>(ei, flag, bcnt, E);
    k_bscan<<<1, 1024, 0, stream>>>(bcnt, bbase, bcur, E);
    // scatter || layer-1 GEMM (independent work, one launch)
    k_scat_gemm1<<<nscat + gb, 256, FUSED_LDS, stream>>>(ei, flag, bcur, eb, E, nscat, x, Wt1, B1b, B1e, N);
    k_build<<<NBUCK, 256, 0, stream>>>(bbase, eb, rowptr, es, dis, N, E);

    // ---- layer 1 aggregation ----
    k_pull128e<true, true><<<pg, 256, 0, stream>>>(rowptr, es, dis, B1e, B1b, b1, B2b, B2e, N);

    // ---- layer 2 ----
    k_gemm_mfma<8, 1, 0><<<gb, 256, 0, stream>>>(B2b, Wt2, B1b, B1e, nullptr, N, 128);
    k_pull128e<true, true><<<pg, 256, 0, stream>>>(rowptr, es, dis, B1e, B1b, b2, B2b, B2e, N);

    // ---- layer 3: aggregate first (A and W3 commute), then GEMM + fused lsm ----
    k_pull128e<false, false><<<pg, 256, 0, stream>>>(rowptr, es, dis, B2e, B2b, nullptr, B1b, nullptr, N);
    k_gemm_mfma<3, 1, 2><<<gb, 256, 0, stream>>>(B1b, Wt3, out, nullptr, b3, N, 40);
}